// Round 1
// baseline (6491.925 us; speedup 1.0000x reference)
//
#include <hip/hip_runtime.h>
#include <math.h>

#define LQ 50        // sequence length
#define DD 200       // model dim
#define DP 202       // padded LDS row stride (floats)
#define NBLK 3       // transformer blocks
#define NT 256       // threads per block

#define NEGC (-4294967295.0f)   // float(-2**32 + 1)

__device__ __forceinline__ float wave_sum(float v) {
  #pragma unroll
  for (int off = 32; off > 0; off >>= 1) v += __shfl_xor(v, off, 64);
  return v;
}
__device__ __forceinline__ float wave_max(float v) {
  #pragma unroll
  for (int off = 32; off > 0; off >>= 1) v = fmaxf(v, __shfl_xor(v, off, 64));
  return v;
}

// dst = (relu?)(src @ W + bias);  src/dst are LDS [LQ][DP], W global [DD][DD], bias [DD]
__device__ __forceinline__ void matmul_50x200(
    const float* __restrict__ src, const float* __restrict__ W,
    const float* __restrict__ bias, float* __restrict__ dst,
    bool do_relu, int tid)
{
  if (tid < 250) {
    const int c4 = tid % 50;            // cols 4*c4 .. 4*c4+3
    const int r0 = (tid / 50) * 10;     // rows r0 .. r0+9
    float acc[10][4];
    #pragma unroll
    for (int i = 0; i < 10; ++i) {
      acc[i][0] = 0.f; acc[i][1] = 0.f; acc[i][2] = 0.f; acc[i][3] = 0.f;
    }
    const float* wp = W + 4 * c4;
    #pragma unroll 2
    for (int k = 0; k < DD; k += 4) {
      float4 w0 = *(const float4*)(wp + (k + 0) * DD);
      float4 w1 = *(const float4*)(wp + (k + 1) * DD);
      float4 w2 = *(const float4*)(wp + (k + 2) * DD);
      float4 w3 = *(const float4*)(wp + (k + 3) * DD);
      #pragma unroll
      for (int i = 0; i < 10; ++i) {
        const float* xp = src + (r0 + i) * DP + k;
        float2 xa = *(const float2*)xp;
        float2 xb = *(const float2*)(xp + 2);
        acc[i][0] += xa.x * w0.x; acc[i][0] += xa.y * w1.x; acc[i][0] += xb.x * w2.x; acc[i][0] += xb.y * w3.x;
        acc[i][1] += xa.x * w0.y; acc[i][1] += xa.y * w1.y; acc[i][1] += xb.x * w2.y; acc[i][1] += xb.y * w3.y;
        acc[i][2] += xa.x * w0.z; acc[i][2] += xa.y * w1.z; acc[i][2] += xb.x * w2.z; acc[i][2] += xb.y * w3.z;
        acc[i][3] += xa.x * w0.w; acc[i][3] += xa.y * w1.w; acc[i][3] += xb.x * w2.w; acc[i][3] += xb.y * w3.w;
      }
    }
    float4 bb = *(const float4*)(bias + 4 * c4);
    #pragma unroll
    for (int i = 0; i < 10; ++i) {
      float v0 = acc[i][0] + bb.x;
      float v1 = acc[i][1] + bb.y;
      float v2 = acc[i][2] + bb.z;
      float v3 = acc[i][3] + bb.w;
      if (do_relu) {
        v0 = fmaxf(v0, 0.f); v1 = fmaxf(v1, 0.f);
        v2 = fmaxf(v2, 0.f); v3 = fmaxf(v3, 0.f);
      }
      float* dp = dst + (r0 + i) * DP + 4 * c4;
      dp[0] = v0; dp[1] = v1; dp[2] = v2; dp[3] = v3;
    }
  }
}

__global__ __launch_bounds__(NT)
void transformer_kernel(const int* __restrict__ tokens,
                        const float* __restrict__ emb,
                        const float* __restrict__ Wq, const float* __restrict__ bq,
                        const float* __restrict__ Wk, const float* __restrict__ bk,
                        const float* __restrict__ Wv, const float* __restrict__ bv,
                        const float* __restrict__ W1, const float* __restrict__ b1,
                        const float* __restrict__ W2, const float* __restrict__ b2,
                        const float* __restrict__ lng, const float* __restrict__ lnb,
                        float* __restrict__ out)
{
  __shared__ float xs[LQ * DP];   // current activations (residual stream)
  __shared__ float q_s[LQ * DP];  // Q   / FFN hidden h1
  __shared__ float k_s[LQ * DP];  // K   / FFN h2 (pre-LN)
  __shared__ float v_s[LQ * DP];  // V
  __shared__ float rowsum[64];    // per-row sum of xs (mask source)
  __shared__ float attnbuf[4 * 64]; // per-wave softmax row

  const int b    = blockIdx.x;
  const int tid  = threadIdx.x;
  const int lane = tid & 63;
  const int wv   = tid >> 6;

  // ---- embedding gather: xs[r][c] = emb[tokens[b][r]][c]
  for (int o2 = tid; o2 < LQ * 100; o2 += NT) {
    int r = o2 / 100, c2 = o2 % 100;
    int tok = tokens[b * LQ + r];
    float2 v = *(const float2*)(emb + (size_t)tok * DD + 2 * c2);
    *(float2*)(xs + r * DP + 2 * c2) = v;
  }
  __syncthreads();

  for (int layer = 0; layer < NBLK; ++layer) {
    const float* wq  = Wq + (size_t)layer * DD * DD;
    const float* wk  = Wk + (size_t)layer * DD * DD;
    const float* wvv = Wv + (size_t)layer * DD * DD;
    const float* w1  = W1 + (size_t)layer * DD * DD;
    const float* w2  = W2 + (size_t)layer * DD * DD;
    const float* bql = bq + layer * DD;
    const float* bkl = bk + layer * DD;
    const float* bvl = bv + layer * DD;
    const float* b1l = b1 + layer * DD;
    const float* b2l = b2 + layer * DD;
    const float* gl  = lng + layer * DD;
    const float* bl  = lnb + layer * DD;

    // ---- row sums of current x (key/query mask source)
    for (int r = wv; r < LQ; r += 4) {
      float s = 0.f;
      #pragma unroll
      for (int t = 0; t < 4; ++t) {
        int c = lane + 64 * t;
        if (c < DD) s += xs[r * DP + c];
      }
      s = wave_sum(s);
      if (lane == 0) rowsum[r] = s;
    }
    // (no barrier needed here: rowsum consumed only after the pre-attention barrier)

    // ---- Q, K, V projections (+bias, relu)
    matmul_50x200(xs, wq,  bql, q_s, true, tid);
    matmul_50x200(xs, wk,  bkl, k_s, true, tid);
    matmul_50x200(xs, wvv, bvl, v_s, true, tid);
    __syncthreads();

    // ---- attention: one wave per q-row
    for (int r = wv; r < LQ; r += 4) {
      // scores: lane j computes q_row . k_row[j]
      float s0 = 0.f, s1 = 0.f, s2 = 0.f, s3 = 0.f;
      if (lane < LQ) {
        const float* qrow = q_s + r * DP;
        const float* krow = k_s + lane * DP;
        #pragma unroll 5
        for (int c = 0; c < DD; c += 8) {
          float2 qa = *(const float2*)(qrow + c);
          float2 qb = *(const float2*)(qrow + c + 2);
          float2 qc = *(const float2*)(qrow + c + 4);
          float2 qd = *(const float2*)(qrow + c + 6);
          float2 ka = *(const float2*)(krow + c);
          float2 kb = *(const float2*)(krow + c + 2);
          float2 kc = *(const float2*)(krow + c + 4);
          float2 kd = *(const float2*)(krow + c + 6);
          s0 += qa.x * ka.x + qa.y * ka.y;
          s1 += qb.x * kb.x + qb.y * kb.y;
          s2 += qc.x * kc.x + qc.y * kc.y;
          s3 += qd.x * kd.x + qd.y * kd.y;
        }
      }
      float sc = ((s0 + s1) + (s2 + s3)) * 0.07071067811865475f; // / sqrt(200)
      float sm = -INFINITY;
      if (lane < LQ) sm = (rowsum[lane] == 0.0f) ? NEGC : sc;

      float m = wave_max(sm);
      float e = (lane < LQ) ? expf(sm - m) : 0.0f;
      float ssum = wave_sum(e);
      float qm = (rowsum[r] == 0.0f) ? 0.0f : 1.0f;
      float a = e / ssum * qm;
      attnbuf[wv * 64 + lane] = a;   // wave-private; intra-wave LDS ordering suffices

      // out row: lane covers cols {2*lane, 2*lane+1} and {128+2*lane, 129+2*lane}
      int c0 = 2 * lane;
      int c1 = 128 + 2 * lane;
      bool act1 = (c1 < DD);
      int c1r = act1 ? c1 : 0;
      float a0x = 0.f, a0y = 0.f, a1x = 0.f, a1y = 0.f;
      #pragma unroll 2
      for (int j = 0; j < LQ; ++j) {
        float aj = attnbuf[wv * 64 + j];
        const float* vp = v_s + j * DP;
        float2 v0 = *(const float2*)(vp + c0);
        float2 v1 = *(const float2*)(vp + c1r);
        a0x += aj * v0.x; a0y += aj * v0.y;
        a1x += aj * v1.x; a1y += aj * v1.y;
      }
      // residual, in-place update of xs row r (only this wave touches row r)
      float* xp = xs + r * DP;
      float2 x0 = *(const float2*)(xp + c0);
      x0.x += a0x; x0.y += a0y;
      *(float2*)(xp + c0) = x0;
      if (act1) {
        float2 x1 = *(const float2*)(xp + c1);
        x1.x += a1x; x1.y += a1y;
        *(float2*)(xp + c1) = x1;
      }
    }
    __syncthreads();

    // ---- FFN: h1 = relu(x@W1+b1) -> q_s ; h2 = h1@W2+b2 -> k_s
    matmul_50x200(xs, w1, b1l, q_s, true, tid);
    __syncthreads();
    matmul_50x200(q_s, w2, b2l, k_s, false, tid);
    __syncthreads();

    // ---- LayerNorm(h2)*g + b + x  -> xs (in place)
    for (int r = wv; r < LQ; r += 4) {
      int c0 = lane, c1 = lane + 64, c2 = lane + 128, c3 = lane + 192;
      float h0 = k_s[r * DP + c0];
      float h1 = k_s[r * DP + c1];
      float h2 = k_s[r * DP + c2];
      float h3 = (c3 < DD) ? k_s[r * DP + c3] : 0.f;
      float mu = wave_sum(h0 + h1 + h2 + h3) * (1.0f / 200.0f);
      float d0 = h0 - mu, d1 = h1 - mu, d2 = h2 - mu;
      float d3 = (c3 < DD) ? (h3 - mu) : 0.f;
      float var = wave_sum(d0 * d0 + d1 * d1 + d2 * d2 + d3 * d3) * (1.0f / 200.0f);
      float inv = 1.0f / sqrtf(var + 1e-8f);
      xs[r * DP + c0] = d0 * inv * gl[c0] + bl[c0] + xs[r * DP + c0];
      xs[r * DP + c1] = d1 * inv * gl[c1] + bl[c1] + xs[r * DP + c1];
      xs[r * DP + c2] = d2 * inv * gl[c2] + bl[c2] + xs[r * DP + c2];
      if (c3 < DD)
        xs[r * DP + c3] = d3 * inv * gl[c3] + bl[c3] + xs[r * DP + c3];
    }
    __syncthreads();
  }

  // ---- write result
  for (int o2 = tid; o2 < LQ * 100; o2 += NT) {
    int r = o2 / 100, c2 = o2 % 100;
    *(float2*)(out + ((size_t)b * LQ + r) * DD + 2 * c2) =
        *(const float2*)(xs + r * DP + 2 * c2);
  }
}

extern "C" void kernel_launch(void* const* d_in, const int* in_sizes, int n_in,
                              void* d_out, int out_size, void* d_ws, size_t ws_size,
                              hipStream_t stream) {
  const int*   tokens = (const int*)  d_in[0];
  const float* emb    = (const float*)d_in[1];
  const float* Wq     = (const float*)d_in[2];
  const float* bq     = (const float*)d_in[3];
  const float* Wk     = (const float*)d_in[4];
  const float* bk     = (const float*)d_in[5];
  const float* Wv     = (const float*)d_in[6];
  const float* bv     = (const float*)d_in[7];
  const float* W1     = (const float*)d_in[8];
  const float* b1     = (const float*)d_in[9];
  const float* W2     = (const float*)d_in[10];
  const float* b2     = (const float*)d_in[11];
  const float* lng    = (const float*)d_in[12];
  const float* lnb    = (const float*)d_in[13];
  float* out = (float*)d_out;

  const int B = in_sizes[0] / LQ;   // 4096
  hipLaunchKernelGGL(transformer_kernel, dim3(B), dim3(NT), 0, stream,
                     tokens, emb, Wq, bq, Wk, bk, Wv, bv, W1, b1, W2, b2,
                     lng, lnb, out);
}

// Round 2
// 6217.326 us; speedup vs baseline: 1.0442x; 1.0442x over previous
//
#include <hip/hip_runtime.h>
#include <math.h>

#define LQ 50        // sequence length
#define DD 200       // model dim
#define DP 202       // padded LDS row stride (floats) for xs/q_s/k_s
#define VP 200       // v_s row stride (un-padded; accesses are row-broadcast)
#define NBLK 3       // transformer blocks
#define NT 512       // threads per block -> 8 waves on the one resident block

#define NEGC (-4294967295.0f)   // float(-2**32 + 1)

__device__ __forceinline__ float wave_sum(float v) {
  #pragma unroll
  for (int off = 32; off > 0; off >>= 1) v += __shfl_xor(v, off, 64);
  return v;
}
__device__ __forceinline__ float wave_max(float v) {
  #pragma unroll
  for (int off = 32; off > 0; off >>= 1) v = fmaxf(v, __shfl_xor(v, off, 64));
  return v;
}

// dst = (relu?)(src @ W + bias); src is LDS [LQ][DP], dst LDS [LQ][dstride],
// W global [DD][DD], bias [DD]. 500 worker threads: 5 rows x 4 cols each.
// k-loop carries a one-iteration-ahead register prefetch of the W tile.
__device__ __forceinline__ void matmul_50x200(
    const float* __restrict__ src, const float* __restrict__ W,
    const float* __restrict__ bias, float* __restrict__ dst,
    bool do_relu, int tid, int dstride)
{
  if (tid < 500) {
    const int c4 = tid % 50;            // cols 4*c4 .. 4*c4+3
    const int r0 = (tid / 50) * 5;      // rows r0 .. r0+4
    float acc[5][4];
    #pragma unroll
    for (int i = 0; i < 5; ++i) {
      acc[i][0] = 0.f; acc[i][1] = 0.f; acc[i][2] = 0.f; acc[i][3] = 0.f;
    }
    const float* wp = W + 4 * c4;
    float4 w0 = *(const float4*)(wp + 0 * DD);
    float4 w1 = *(const float4*)(wp + 1 * DD);
    float4 w2 = *(const float4*)(wp + 2 * DD);
    float4 w3 = *(const float4*)(wp + 3 * DD);
    for (int k = 0; k < DD; k += 4) {
      const int kn = (k + 4 < DD) ? (k + 4) : 0;   // harmless wrap on last iter
      float4 n0 = *(const float4*)(wp + (kn + 0) * DD);
      float4 n1 = *(const float4*)(wp + (kn + 1) * DD);
      float4 n2 = *(const float4*)(wp + (kn + 2) * DD);
      float4 n3 = *(const float4*)(wp + (kn + 3) * DD);
      #pragma unroll
      for (int i = 0; i < 5; ++i) {
        const float* xp = src + (r0 + i) * DP + k;
        float2 xa = *(const float2*)xp;
        float2 xb = *(const float2*)(xp + 2);
        acc[i][0] += xa.x * w0.x; acc[i][0] += xa.y * w1.x; acc[i][0] += xb.x * w2.x; acc[i][0] += xb.y * w3.x;
        acc[i][1] += xa.x * w0.y; acc[i][1] += xa.y * w1.y; acc[i][1] += xb.x * w2.y; acc[i][1] += xb.y * w3.y;
        acc[i][2] += xa.x * w0.z; acc[i][2] += xa.y * w1.z; acc[i][2] += xb.x * w2.z; acc[i][2] += xb.y * w3.z;
        acc[i][3] += xa.x * w0.w; acc[i][3] += xa.y * w1.w; acc[i][3] += xb.x * w2.w; acc[i][3] += xb.y * w3.w;
      }
      w0 = n0; w1 = n1; w2 = n2; w3 = n3;
    }
    float4 bb = *(const float4*)(bias + 4 * c4);
    #pragma unroll
    for (int i = 0; i < 5; ++i) {
      float v0 = acc[i][0] + bb.x;
      float v1 = acc[i][1] + bb.y;
      float v2 = acc[i][2] + bb.z;
      float v3 = acc[i][3] + bb.w;
      if (do_relu) {
        v0 = fmaxf(v0, 0.f); v1 = fmaxf(v1, 0.f);
        v2 = fmaxf(v2, 0.f); v3 = fmaxf(v3, 0.f);
      }
      float* dp = dst + (r0 + i) * dstride + 4 * c4;
      dp[0] = v0; dp[1] = v1; dp[2] = v2; dp[3] = v3;
    }
  }
}

__global__ __launch_bounds__(NT)
void transformer_kernel(const int* __restrict__ tokens,
                        const float* __restrict__ emb,
                        const float* __restrict__ Wq, const float* __restrict__ bq,
                        const float* __restrict__ Wk, const float* __restrict__ bk,
                        const float* __restrict__ Wv, const float* __restrict__ bv,
                        const float* __restrict__ W1, const float* __restrict__ b1,
                        const float* __restrict__ W2, const float* __restrict__ b2,
                        const float* __restrict__ lng, const float* __restrict__ lnb,
                        float* __restrict__ out)
{
  __shared__ float xs[LQ * DP];    // residual stream
  __shared__ float q_s[LQ * DP];   // Q   / FFN hidden h1
  __shared__ float k_s[LQ * DP];   // K   / FFN h2 (pre-LN)
  __shared__ float v_s[LQ * VP];   // V
  __shared__ float rowsum[52];     // per-row sum of xs (mask source)
  __shared__ float attnbuf[8 * 52];// per-wave softmax row

  const int b    = blockIdx.x;
  const int tid  = threadIdx.x;
  const int lane = tid & 63;
  const int wv   = tid >> 6;

  // ---- embedding gather: xs[r][c] = emb[tokens[b][r]][c]
  for (int o2 = tid; o2 < LQ * 100; o2 += NT) {
    int r = o2 / 100, c2 = o2 % 100;
    int tok = tokens[b * LQ + r];
    float2 v = *(const float2*)(emb + (size_t)tok * DD + 2 * c2);
    *(float2*)(xs + r * DP + 2 * c2) = v;
  }
  __syncthreads();

  for (int layer = 0; layer < NBLK; ++layer) {
    const float* wq  = Wq + (size_t)layer * DD * DD;
    const float* wk  = Wk + (size_t)layer * DD * DD;
    const float* wvv = Wv + (size_t)layer * DD * DD;
    const float* w1  = W1 + (size_t)layer * DD * DD;
    const float* w2  = W2 + (size_t)layer * DD * DD;
    const float* bql = bq + layer * DD;
    const float* bkl = bk + layer * DD;
    const float* bvl = bv + layer * DD;
    const float* b1l = b1 + layer * DD;
    const float* b2l = b2 + layer * DD;
    const float* gl  = lng + layer * DD;
    const float* bl  = lnb + layer * DD;

    // ---- row sums of current x (key/query mask source)
    for (int r = wv; r < LQ; r += 8) {
      float s = 0.f;
      #pragma unroll
      for (int t = 0; t < 4; ++t) {
        int c = lane + 64 * t;
        if (c < DD) s += xs[r * DP + c];
      }
      s = wave_sum(s);
      if (lane == 0) rowsum[r] = s;
    }
    // rowsum consumed only after the post-projection barrier

    // ---- Q, K, V projections (+bias, relu)
    matmul_50x200(xs, wq,  bql, q_s, true, tid, DP);
    matmul_50x200(xs, wk,  bkl, k_s, true, tid, DP);
    matmul_50x200(xs, wvv, bvl, v_s, true, tid, VP);
    __syncthreads();

    // ---- attention: one wave per q-row
    for (int r = wv; r < LQ; r += 8) {
      // scores: lane j computes q_row . k_row[j]
      float s0 = 0.f, s1 = 0.f, s2 = 0.f, s3 = 0.f;
      if (lane < LQ) {
        const float* qrow = q_s + r * DP;
        const float* krow = k_s + lane * DP;
        #pragma unroll 5
        for (int c = 0; c < DD; c += 8) {
          float2 qa = *(const float2*)(qrow + c);
          float2 qb = *(const float2*)(qrow + c + 2);
          float2 qc = *(const float2*)(qrow + c + 4);
          float2 qd = *(const float2*)(qrow + c + 6);
          float2 ka = *(const float2*)(krow + c);
          float2 kb = *(const float2*)(krow + c + 2);
          float2 kc = *(const float2*)(krow + c + 4);
          float2 kd = *(const float2*)(krow + c + 6);
          s0 += qa.x * ka.x + qa.y * ka.y;
          s1 += qb.x * kb.x + qb.y * kb.y;
          s2 += qc.x * kc.x + qc.y * kc.y;
          s3 += qd.x * kd.x + qd.y * kd.y;
        }
      }
      float sc = ((s0 + s1) + (s2 + s3)) * 0.07071067811865475f; // / sqrt(200)
      float sm = -INFINITY;
      if (lane < LQ) sm = (rowsum[lane] == 0.0f) ? NEGC : sc;

      float m = wave_max(sm);
      float e = (lane < LQ) ? expf(sm - m) : 0.0f;
      float ssum = wave_sum(e);
      float qm = (rowsum[r] == 0.0f) ? 0.0f : 1.0f;
      float a = e / ssum * qm;
      if (lane < LQ) attnbuf[wv * 52 + lane] = a;  // wave-private row

      // out row: lane covers cols {2*lane, 2*lane+1} and {128+2*lane, 129+2*lane}
      int c0 = 2 * lane;
      int c1 = 128 + 2 * lane;
      bool act1 = (c1 < DD);
      int c1r = act1 ? c1 : 0;
      float a0x = 0.f, a0y = 0.f, a1x = 0.f, a1y = 0.f;
      #pragma unroll 2
      for (int j = 0; j < LQ; ++j) {
        float aj = attnbuf[wv * 52 + j];
        const float* vp = v_s + j * VP;
        float2 v0 = *(const float2*)(vp + c0);
        float2 v1 = *(const float2*)(vp + c1r);
        a0x += aj * v0.x; a0y += aj * v0.y;
        a1x += aj * v1.x; a1y += aj * v1.y;
      }
      // residual, in-place update of xs row r (only this wave touches row r)
      float* xp = xs + r * DP;
      float2 x0 = *(const float2*)(xp + c0);
      x0.x += a0x; x0.y += a0y;
      *(float2*)(xp + c0) = x0;
      if (act1) {
        float2 x1 = *(const float2*)(xp + c1);
        x1.x += a1x; x1.y += a1y;
        *(float2*)(xp + c1) = x1;
      }
    }
    __syncthreads();

    // ---- FFN: h1 = relu(x@W1+b1) -> q_s ; h2 = h1@W2+b2 -> k_s
    matmul_50x200(xs, w1, b1l, q_s, true, tid, DP);
    __syncthreads();
    matmul_50x200(q_s, w2, b2l, k_s, false, tid, DP);
    __syncthreads();

    // ---- LayerNorm(h2)*g + b + x  -> xs (in place)
    for (int r = wv; r < LQ; r += 8) {
      int c0 = lane, c1 = lane + 64, c2 = lane + 128, c3 = lane + 192;
      float h0 = k_s[r * DP + c0];
      float h1 = k_s[r * DP + c1];
      float h2 = k_s[r * DP + c2];
      float h3 = (c3 < DD) ? k_s[r * DP + c3] : 0.f;
      float mu = wave_sum(h0 + h1 + h2 + h3) * (1.0f / 200.0f);
      float d0 = h0 - mu, d1 = h1 - mu, d2 = h2 - mu;
      float d3 = (c3 < DD) ? (h3 - mu) : 0.f;
      float var = wave_sum(d0 * d0 + d1 * d1 + d2 * d2 + d3 * d3) * (1.0f / 200.0f);
      float inv = 1.0f / sqrtf(var + 1e-8f);
      xs[r * DP + c0] = d0 * inv * gl[c0] + bl[c0] + xs[r * DP + c0];
      xs[r * DP + c1] = d1 * inv * gl[c1] + bl[c1] + xs[r * DP + c1];
      xs[r * DP + c2] = d2 * inv * gl[c2] + bl[c2] + xs[r * DP + c2];
      if (c3 < DD)
        xs[r * DP + c3] = d3 * inv * gl[c3] + bl[c3] + xs[r * DP + c3];
    }
    __syncthreads();
  }

  // ---- write result
  for (int o2 = tid; o2 < LQ * 100; o2 += NT) {
    int r = o2 / 100, c2 = o2 % 100;
    *(float2*)(out + ((size_t)b * LQ + r) * DD + 2 * c2) =
        *(const float2*)(xs + r * DP + 2 * c2);
  }
}

extern "C" void kernel_launch(void* const* d_in, const int* in_sizes, int n_in,
                              void* d_out, int out_size, void* d_ws, size_t ws_size,
                              hipStream_t stream) {
  const int*   tokens = (const int*)  d_in[0];
  const float* emb    = (const float*)d_in[1];
  const float* Wq     = (const float*)d_in[2];
  const float* bq     = (const float*)d_in[3];
  const float* Wk     = (const float*)d_in[4];
  const float* bk     = (const float*)d_in[5];
  const float* Wv     = (const float*)d_in[6];
  const float* bv     = (const float*)d_in[7];
  const float* W1     = (const float*)d_in[8];
  const float* b1     = (const float*)d_in[9];
  const float* W2     = (const float*)d_in[10];
  const float* b2     = (const float*)d_in[11];
  const float* lng    = (const float*)d_in[12];
  const float* lnb    = (const float*)d_in[13];
  float* out = (float*)d_out;

  const int B = in_sizes[0] / LQ;   // 4096
  hipLaunchKernelGGL(transformer_kernel, dim3(B), dim3(NT), 0, stream,
                     tokens, emb, Wq, bq, Wk, bk, Wv, bv, W1, b1, W2, b2,
                     lng, lnb, out);
}

// Round 3
// 3433.884 us; speedup vs baseline: 1.8905x; 1.8106x over previous
//
#include <hip/hip_runtime.h>
#include <math.h>

#define LQ 50        // sequence length
#define DD 200       // model dim
#define XP 204       // stride for matmul-source LDS tiles (16B-aligned rows)
#define KP 202       // k_s stride (h2 / K buffer; never a matmul source)
#define VP 200       // v_s stride
#define NBLK 3
#define NT 512       // 8 waves

#define KT 7         // k-tiles of 32  (224 >= 200)
#define NTL 14       // n-tiles of 16  (224 >= 200; tile 13 zero-padded)
#define MAT_U (KT * NTL * 128)   // s16x8 units per matrix (12544 -> 200704 B)

#define NEGC (-4294967295.0f)

typedef __attribute__((ext_vector_type(4))) float f32x4;
typedef __attribute__((ext_vector_type(8))) short s16x8;

__device__ __forceinline__ unsigned short bf16_rne(float x) {
  unsigned u = __float_as_uint(x);
  unsigned r = u + 0x7FFF + ((u >> 16) & 1);
  return (unsigned short)(r >> 16);
}
__device__ __forceinline__ float bf16_f(unsigned short h) {
  return __uint_as_float((unsigned)h << 16);
}

__device__ __forceinline__ float wave_sum(float v) {
  #pragma unroll
  for (int off = 32; off > 0; off >>= 1) v += __shfl_xor(v, off, 64);
  return v;
}
__device__ __forceinline__ float wave_max(float v) {
  #pragma unroll
  for (int off = 32; off > 0; off >>= 1) v = fmaxf(v, __shfl_xor(v, off, 64));
  return v;
}

// ---------------- pre-swizzle: W f32 [DD][DD] -> bf16 hi/lo fragment chunks ----
// chunk layout: [mat][kt][nt][h(0=hi,1=lo)][lane][8 bf16]; 16B per lane per chunk.
// fragment k-map: slot (g = lane>>4, j) <-> k = kt*32 + g*8 + j  (same map used
// for A on the consumer side -> correctness independent of HW's internal k map).
__global__ __launch_bounds__(64)
void swizzle_w(const float* __restrict__ Wq, const float* __restrict__ Wk,
               const float* __restrict__ Wv, const float* __restrict__ W1,
               const float* __restrict__ W2, unsigned short* __restrict__ wbuf)
{
  int t = blockIdx.x;             // 15*KT*NTL blocks
  int nt = t % NTL; t /= NTL;
  int kt = t % KT;  t /= KT;
  int mat = t;                    // layer*5 + {0..4}
  int layer = mat / 5, which = mat % 5;
  const float* W;
  switch (which) {
    case 0: W = Wq; break;
    case 1: W = Wk; break;
    case 2: W = Wv; break;
    case 3: W = W1; break;
    default: W = W2; break;
  }
  W += (size_t)layer * DD * DD;

  const int l = threadIdx.x;
  const int g = l >> 4, c = l & 15;
  const int n = nt * 16 + c;
  s16x8 vh, vl;
  #pragma unroll
  for (int j = 0; j < 8; ++j) {
    int k = kt * 32 + g * 8 + j;
    float w = (k < DD && n < DD) ? W[k * DD + n] : 0.0f;
    unsigned short h = bf16_rne(w);
    unsigned short lo = bf16_rne(w - bf16_f(h));
    vh[j] = (short)h;
    vl[j] = (short)lo;
  }
  size_t base = ((size_t)(mat * KT * NTL + kt * NTL + nt) * 2) * 512 + l * 8;
  *(s16x8*)(wbuf + base)       = vh;
  *(s16x8*)(wbuf + base + 512) = vl;
}

// ---------------- MFMA matmul: dst = (relu?)(src @ W + bias) -------------------
// src: LDS f32, stride XP. wt: swizzled matrix base (s16x8 units).
// wave wv owns m-tile (wv>>1); n-halves 0..6 / 7..13.
__device__ __forceinline__ void matmul_mfma(
    const float* __restrict__ src, const s16x8* __restrict__ wt,
    const float* __restrict__ bias, float* __restrict__ dst, int dstride,
    bool do_relu, int wv, int lane)
{
  const int mt   = wv >> 1;
  const int nt0  = (wv & 1) * 7;
  const int g    = lane >> 4, c = lane & 15;
  const float* xrow = src + (mt * 16 + c) * XP;   // rows >=50 read garbage: harmless

  f32x4 acc[7];
  #pragma unroll
  for (int i = 0; i < 7; ++i) acc[i] = (f32x4)0.0f;

  #pragma unroll 1
  for (int kt = 0; kt < KT; ++kt) {
    // B fragments for this k-tile (global, L2-hot, coalesced 16B/lane)
    const s16x8* tp = wt + (size_t)(kt * NTL + nt0) * 128 + lane;
    s16x8 bh[7], bl[7];
    #pragma unroll
    for (int i = 0; i < 7; ++i) {
      bh[i] = tp[i * 128];
      bl[i] = tp[i * 128 + 64];
    }
    // A fragment (hi/lo) from LDS f32, slot k-map matches pre-swizzle
    const int k0 = kt * 32 + g * 8;
    s16x8 ah = (s16x8)0, al = (s16x8)0;
    if (k0 < DD) {                       // kt<6 always; kt==6 only g==0
      float xv[8];
      *(float4*)&xv[0] = *(const float4*)(xrow + k0);
      *(float4*)&xv[4] = *(const float4*)(xrow + k0 + 4);
      #pragma unroll
      for (int j = 0; j < 8; ++j) {
        unsigned short h = bf16_rne(xv[j]);
        ah[j] = (short)h;
        al[j] = (short)bf16_rne(xv[j] - bf16_f(h));
      }
    }
    #pragma unroll
    for (int i = 0; i < 7; ++i) {
      acc[i] = __builtin_amdgcn_mfma_f32_16x16x32_bf16(ah, bh[i], acc[i], 0, 0, 0);
      acc[i] = __builtin_amdgcn_mfma_f32_16x16x32_bf16(al, bh[i], acc[i], 0, 0, 0);
      acc[i] = __builtin_amdgcn_mfma_f32_16x16x32_bf16(ah, bl[i], acc[i], 0, 0, 0);
    }
  }

  // epilogue: C lane map col = lane&15, row = (lane>>4)*4 + reg  [m89-verified]
  #pragma unroll
  for (int i = 0; i < 7; ++i) {
    int col = (nt0 + i) * 16 + c;
    if (col < DD) {
      float bv = bias[col];
      #pragma unroll
      for (int q = 0; q < 4; ++q) {
        int r = mt * 16 + g * 4 + q;
        if (r < LQ) {
          float v = acc[i][q] + bv;
          if (do_relu) v = fmaxf(v, 0.f);
          dst[r * dstride + col] = v;
        }
      }
    }
  }
}

__global__ __launch_bounds__(NT)
void transformer_kernel(const int* __restrict__ tokens,
                        const float* __restrict__ emb,
                        const unsigned short* __restrict__ wbuf,
                        const float* __restrict__ bq, const float* __restrict__ bk,
                        const float* __restrict__ bv, const float* __restrict__ b1,
                        const float* __restrict__ b2,
                        const float* __restrict__ lng, const float* __restrict__ lnb,
                        float* __restrict__ out)
{
  __shared__ __align__(16) float xs[LQ * XP];   // residual stream (matmul src)
  __shared__ __align__(16) float q_s[LQ * XP];  // Q / h1 (matmul src)
  __shared__ __align__(16) float k_s[LQ * KP];  // K / h2
  __shared__ __align__(16) float v_s[LQ * VP];  // V
  __shared__ float rowsum[LQ];
  __shared__ float attnbuf[8 * LQ];

  const int b    = blockIdx.x;
  const int tid  = threadIdx.x;
  const int lane = tid & 63;
  const int wv   = tid >> 6;

  // ---- embedding gather
  for (int o2 = tid; o2 < LQ * 100; o2 += NT) {
    int r = o2 / 100, c2 = o2 % 100;
    int tok = tokens[b * LQ + r];
    float2 v = *(const float2*)(emb + (size_t)tok * DD + 2 * c2);
    *(float2*)(xs + r * XP + 2 * c2) = v;
  }
  __syncthreads();

  for (int layer = 0; layer < NBLK; ++layer) {
    const s16x8* wq  = (const s16x8*)wbuf + (size_t)(layer * 5 + 0) * MAT_U;
    const s16x8* wk  = (const s16x8*)wbuf + (size_t)(layer * 5 + 1) * MAT_U;
    const s16x8* wvv = (const s16x8*)wbuf + (size_t)(layer * 5 + 2) * MAT_U;
    const s16x8* w1  = (const s16x8*)wbuf + (size_t)(layer * 5 + 3) * MAT_U;
    const s16x8* w2  = (const s16x8*)wbuf + (size_t)(layer * 5 + 4) * MAT_U;
    const float* bql = bq + layer * DD;
    const float* bkl = bk + layer * DD;
    const float* bvl = bv + layer * DD;
    const float* b1l = b1 + layer * DD;
    const float* b2l = b2 + layer * DD;
    const float* gl  = lng + layer * DD;
    const float* bl  = lnb + layer * DD;

    // ---- row sums (mask source); consumed after the post-QKV barrier
    for (int r = wv; r < LQ; r += 8) {
      float s = 0.f;
      #pragma unroll
      for (int t = 0; t < 4; ++t) {
        int cc = lane + 64 * t;
        if (cc < DD) s += xs[r * XP + cc];
      }
      s = wave_sum(s);
      if (lane == 0) rowsum[r] = s;
    }

    // ---- Q, K, V projections via MFMA
    matmul_mfma(xs, wq,  bql, q_s, XP, true, wv, lane);
    matmul_mfma(xs, wk,  bkl, k_s, KP, true, wv, lane);
    matmul_mfma(xs, wvv, bvl, v_s, VP, true, wv, lane);
    __syncthreads();

    // ---- attention: one wave per q-row (vector f32)
    for (int r = wv; r < LQ; r += 8) {
      float s0 = 0.f, s1 = 0.f, s2 = 0.f, s3 = 0.f;
      if (lane < LQ) {
        const float* qrow = q_s + r * XP;
        const float* krow = k_s + lane * KP;
        #pragma unroll 5
        for (int c = 0; c < DD; c += 8) {
          float2 qa = *(const float2*)(qrow + c);
          float2 qb = *(const float2*)(qrow + c + 2);
          float2 qc = *(const float2*)(qrow + c + 4);
          float2 qd = *(const float2*)(qrow + c + 6);
          float2 ka = *(const float2*)(krow + c);
          float2 kb = *(const float2*)(krow + c + 2);
          float2 kc = *(const float2*)(krow + c + 4);
          float2 kd = *(const float2*)(krow + c + 6);
          s0 += qa.x * ka.x + qa.y * ka.y;
          s1 += qb.x * kb.x + qb.y * kb.y;
          s2 += qc.x * kc.x + qc.y * kc.y;
          s3 += qd.x * kd.x + qd.y * kd.y;
        }
      }
      float sc = ((s0 + s1) + (s2 + s3)) * 0.07071067811865475f;
      float sm = -INFINITY;
      if (lane < LQ) sm = (rowsum[lane] == 0.0f) ? NEGC : sc;

      float m = wave_max(sm);
      float e = (lane < LQ) ? expf(sm - m) : 0.0f;
      float ssum = wave_sum(e);
      float qm = (rowsum[r] == 0.0f) ? 0.0f : 1.0f;
      float a = e / ssum * qm;
      if (lane < LQ) attnbuf[wv * LQ + lane] = a;

      int c0 = 2 * lane;
      int c1 = 128 + 2 * lane;
      bool act1 = (c1 < DD);
      int c1r = act1 ? c1 : 0;
      float a0x = 0.f, a0y = 0.f, a1x = 0.f, a1y = 0.f;
      #pragma unroll 2
      for (int j = 0; j < LQ; ++j) {
        float aj = attnbuf[wv * LQ + j];
        const float* vp = v_s + j * VP;
        float2 v0 = *(const float2*)(vp + c0);
        float2 v1 = *(const float2*)(vp + c1r);
        a0x += aj * v0.x; a0y += aj * v0.y;
        a1x += aj * v1.x; a1y += aj * v1.y;
      }
      float* xp = xs + r * XP;
      float2 x0 = *(const float2*)(xp + c0);
      x0.x += a0x; x0.y += a0y;
      *(float2*)(xp + c0) = x0;
      if (act1) {
        float2 x1 = *(const float2*)(xp + c1);
        x1.x += a1x; x1.y += a1y;
        *(float2*)(xp + c1) = x1;
      }
    }
    __syncthreads();

    // ---- FFN
    matmul_mfma(xs, w1, b1l, q_s, XP, true, wv, lane);
    __syncthreads();
    matmul_mfma(q_s, w2, b2l, k_s, KP, false, wv, lane);
    __syncthreads();

    // ---- LayerNorm(h2)*g + b + x -> xs
    for (int r = wv; r < LQ; r += 8) {
      int c0 = lane, c1 = lane + 64, c2 = lane + 128, c3 = lane + 192;
      float h0 = k_s[r * KP + c0];
      float h1 = k_s[r * KP + c1];
      float h2 = k_s[r * KP + c2];
      float h3 = (c3 < DD) ? k_s[r * KP + c3] : 0.f;
      float mu = wave_sum(h0 + h1 + h2 + h3) * (1.0f / 200.0f);
      float d0 = h0 - mu, d1 = h1 - mu, d2 = h2 - mu;
      float d3 = (c3 < DD) ? (h3 - mu) : 0.f;
      float var = wave_sum(d0 * d0 + d1 * d1 + d2 * d2 + d3 * d3) * (1.0f / 200.0f);
      float inv = 1.0f / sqrtf(var + 1e-8f);
      xs[r * XP + c0] = d0 * inv * gl[c0] + bl[c0] + xs[r * XP + c0];
      xs[r * XP + c1] = d1 * inv * gl[c1] + bl[c1] + xs[r * XP + c1];
      xs[r * XP + c2] = d2 * inv * gl[c2] + bl[c2] + xs[r * XP + c2];
      if (c3 < DD)
        xs[r * XP + c3] = d3 * inv * gl[c3] + bl[c3] + xs[r * XP + c3];
    }
    __syncthreads();
  }

  // ---- write result
  for (int o2 = tid; o2 < LQ * 100; o2 += NT) {
    int r = o2 / 100, c2 = o2 % 100;
    *(float2*)(out + ((size_t)b * LQ + r) * DD + 2 * c2) =
        *(const float2*)(xs + r * XP + 2 * c2);
  }
}

extern "C" void kernel_launch(void* const* d_in, const int* in_sizes, int n_in,
                              void* d_out, int out_size, void* d_ws, size_t ws_size,
                              hipStream_t stream) {
  const int*   tokens = (const int*)  d_in[0];
  const float* emb    = (const float*)d_in[1];
  const float* Wq     = (const float*)d_in[2];
  const float* bq     = (const float*)d_in[3];
  const float* Wk     = (const float*)d_in[4];
  const float* bk     = (const float*)d_in[5];
  const float* Wv     = (const float*)d_in[6];
  const float* bv     = (const float*)d_in[7];
  const float* W1     = (const float*)d_in[8];
  const float* b1     = (const float*)d_in[9];
  const float* W2     = (const float*)d_in[10];
  const float* b2     = (const float*)d_in[11];
  const float* lng    = (const float*)d_in[12];
  const float* lnb    = (const float*)d_in[13];
  float* out = (float*)d_out;
  unsigned short* wbuf = (unsigned short*)d_ws;   // 15 * 200704 B = 2.87 MB

  hipLaunchKernelGGL(swizzle_w, dim3(15 * KT * NTL), dim3(64), 0, stream,
                     Wq, Wk, Wv, W1, W2, wbuf);

  const int B = in_sizes[0] / LQ;   // 4096
  hipLaunchKernelGGL(transformer_kernel, dim3(B), dim3(NT), 0, stream,
                     tokens, emb, wbuf, bq, bk, bv, b1, b2, lng, lnb, out);
}

// Round 4
// 2685.388 us; speedup vs baseline: 2.4175x; 1.2787x over previous
//
#include <hip/hip_runtime.h>
#include <math.h>

#define LQ 50        // sequence length
#define DD 200       // model dim
#define XP 204       // xs / q_s row stride (f32)
#define KP 200       // k_s row stride
#define VTP 52       // v_T row stride (cols = key index j)
#define SP 68        // S row stride (inside q_s)
#define NBLK 3
#define NT 512       // 8 waves

#define KT 7         // k-tiles of 32 (224 >= 200)
#define NTL 14       // wbuf n-tile layout count
#define MAT_U (KT * NTL * 128)   // s16x8 units per matrix

#define NEGC (-4294967295.0f)
#define SCALE 0.07071067811865475f

typedef __attribute__((ext_vector_type(4))) float f32x4;
typedef __attribute__((ext_vector_type(8))) short s16x8;

__device__ __forceinline__ unsigned short bf16_rne(float x) {
  unsigned u = __float_as_uint(x);
  unsigned r = u + 0x7FFF + ((u >> 16) & 1);
  return (unsigned short)(r >> 16);
}
__device__ __forceinline__ float bf16_f(unsigned short h) {
  return __uint_as_float((unsigned)h << 16);
}

__device__ __forceinline__ float wave_sum(float v) {
  #pragma unroll
  for (int off = 32; off > 0; off >>= 1) v += __shfl_xor(v, off, 64);
  return v;
}
__device__ __forceinline__ float wave_max(float v) {
  #pragma unroll
  for (int off = 32; off > 0; off >>= 1) v = fmaxf(v, __shfl_xor(v, off, 64));
  return v;
}

// pack 8 consecutive f32 (16B-aligned) -> hi/lo bf16 fragments
__device__ __forceinline__ void pack8(const float* __restrict__ p, s16x8& h, s16x8& l) {
  float xv[8];
  *(float4*)&xv[0] = *(const float4*)p;
  *(float4*)&xv[4] = *(const float4*)(p + 4);
  #pragma unroll
  for (int j = 0; j < 8; ++j) {
    unsigned short hh = bf16_rne(xv[j]);
    h[j] = (short)hh;
    l[j] = (short)bf16_rne(xv[j] - bf16_f(hh));
  }
}
// same, but slots with k0+j >= LQ forced to zero (kills 0*NaN from pad reads)
__device__ __forceinline__ void pack8_mask(const float* __restrict__ p, int k0,
                                           s16x8& h, s16x8& l) {
  float xv[8];
  *(float4*)&xv[0] = *(const float4*)p;
  *(float4*)&xv[4] = *(const float4*)(p + 4);
  #pragma unroll
  for (int j = 0; j < 8; ++j) {
    float x = (k0 + j < LQ) ? xv[j] : 0.0f;
    unsigned short hh = bf16_rne(x);
    h[j] = (short)hh;
    l[j] = (short)bf16_rne(x - bf16_f(hh));
  }
}

// ---------------- pre-swizzle: W f32 [DD][DD] -> bf16 hi/lo fragment chunks ----
__global__ __launch_bounds__(64)
void swizzle_w(const float* __restrict__ Wq, const float* __restrict__ Wk,
               const float* __restrict__ Wv, const float* __restrict__ W1,
               const float* __restrict__ W2, unsigned short* __restrict__ wbuf)
{
  int t = blockIdx.x;             // 15*KT*NTL blocks
  int nt = t % NTL; t /= NTL;
  int kt = t % KT;  t /= KT;
  int mat = t;
  int layer = mat / 5, which = mat % 5;
  const float* W;
  switch (which) {
    case 0: W = Wq; break;
    case 1: W = Wk; break;
    case 2: W = Wv; break;
    case 3: W = W1; break;
    default: W = W2; break;
  }
  W += (size_t)layer * DD * DD;

  const int l = threadIdx.x;
  const int g = l >> 4, c = l & 15;
  const int n = nt * 16 + c;
  s16x8 vh, vl;
  #pragma unroll
  for (int j = 0; j < 8; ++j) {
    int k = kt * 32 + g * 8 + j;
    float w = (k < DD && n < DD) ? W[k * DD + n] : 0.0f;
    unsigned short h = bf16_rne(w);
    unsigned short lo = bf16_rne(w - bf16_f(h));
    vh[j] = (short)h;
    vl[j] = (short)lo;
  }
  size_t base = ((size_t)(mat * KT * NTL + kt * NTL + nt) * 2) * 512 + l * 8;
  *(s16x8*)(wbuf + base)       = vh;
  *(s16x8*)(wbuf + base + 512) = vl;
}

// ---------------- MFMA matmul: dst = (relu?)(src @ W + bias) -------------------
// src: LDS f32 stride XP. tdst: write transposed (dst[col*VTP + r]).
__device__ __forceinline__ void matmul_mfma(
    const float* __restrict__ src, const s16x8* __restrict__ wt,
    const float* __restrict__ bias, float* __restrict__ dst, int dstride,
    bool do_relu, bool tdst, int wv, int lane)
{
  const int mt  = wv >> 1;
  const int nt0 = (wv & 1) * 7;
  const int nte = nt0 ? 6 : 7;          // global nt 13 is pure padding: skip
  const int g = lane >> 4, c = lane & 15;
  int ar = mt * 16 + c; if (ar >= LQ) ar = 0;
  const float* xrow = src + ar * XP;

  f32x4 acc[7];
  #pragma unroll
  for (int i = 0; i < 7; ++i) acc[i] = (f32x4)0.0f;

  #pragma unroll 1
  for (int kt = 0; kt < KT; ++kt) {
    const s16x8* tp = wt + (size_t)(kt * NTL + nt0) * 128 + lane;
    s16x8 bh[7], bl[7];
    #pragma unroll
    for (int i = 0; i < 7; ++i) {
      if (i < nte) { bh[i] = tp[i * 128]; bl[i] = tp[i * 128 + 64]; }
    }
    const int k0 = kt * 32 + g * 8;
    s16x8 ah = (s16x8)0, al = (s16x8)0;
    if (k0 < DD) pack8(xrow + k0, ah, al);
    #pragma unroll
    for (int i = 0; i < 7; ++i) {
      if (i < nte) {
        acc[i] = __builtin_amdgcn_mfma_f32_16x16x32_bf16(ah, bh[i], acc[i], 0, 0, 0);
        acc[i] = __builtin_amdgcn_mfma_f32_16x16x32_bf16(al, bh[i], acc[i], 0, 0, 0);
        acc[i] = __builtin_amdgcn_mfma_f32_16x16x32_bf16(ah, bl[i], acc[i], 0, 0, 0);
      }
    }
  }

  #pragma unroll
  for (int i = 0; i < 7; ++i) {
    if (i < nte) {
      int col = (nt0 + i) * 16 + c;
      if (col < DD) {
        float bv = bias[col];
        #pragma unroll
        for (int q = 0; q < 4; ++q) {
          int r = mt * 16 + g * 4 + q;
          if (r < LQ) {
            float v = acc[i][q] + bv;
            if (do_relu) v = fmaxf(v, 0.f);
            if (tdst) dst[col * VTP + r] = v;
            else      dst[r * dstride + col] = v;
          }
        }
      }
    }
  }
}

__global__ __launch_bounds__(NT, 2)
void transformer_kernel(const int* __restrict__ tokens,
                        const float* __restrict__ emb,
                        const unsigned short* __restrict__ wbuf,
                        const float* __restrict__ bq, const float* __restrict__ bk,
                        const float* __restrict__ bv, const float* __restrict__ b1,
                        const float* __restrict__ b2,
                        const float* __restrict__ lng, const float* __restrict__ lnb,
                        float* __restrict__ out)
{
  __shared__ __align__(16) float v_T[DD * VTP];   // V^T  [d][j]   41600 B
  __shared__ __align__(16) float xs[LQ * XP];     // residual      40800 B
  __shared__ __align__(16) float q_s[LQ * XP];    // Q / S / h1    40800 B
  __shared__ __align__(16) float k_s[LQ * KP];    // K / h2        40000 B
  __shared__ float rowsum[52];

  const int b    = blockIdx.x;
  const int tid  = threadIdx.x;
  const int lane = tid & 63;
  const int wv   = tid >> 6;
  const int g    = lane >> 4, c = lane & 15;

  // ---- embedding gather
  for (int o2 = tid; o2 < LQ * 100; o2 += NT) {
    int r = o2 / 100, c2 = o2 % 100;
    int tok = tokens[b * LQ + r];
    float2 v = *(const float2*)(emb + (size_t)tok * DD + 2 * c2);
    *(float2*)(xs + r * XP + 2 * c2) = v;
  }
  __syncthreads();

  for (int layer = 0; layer < NBLK; ++layer) {
    const s16x8* wq  = (const s16x8*)wbuf + (size_t)(layer * 5 + 0) * MAT_U;
    const s16x8* wk  = (const s16x8*)wbuf + (size_t)(layer * 5 + 1) * MAT_U;
    const s16x8* wvv = (const s16x8*)wbuf + (size_t)(layer * 5 + 2) * MAT_U;
    const s16x8* w1  = (const s16x8*)wbuf + (size_t)(layer * 5 + 3) * MAT_U;
    const s16x8* w2  = (const s16x8*)wbuf + (size_t)(layer * 5 + 4) * MAT_U;
    const float* bql = bq + layer * DD;
    const float* bkl = bk + layer * DD;
    const float* bvl = bv + layer * DD;
    const float* b1l = b1 + layer * DD;
    const float* b2l = b2 + layer * DD;
    const float* gl  = lng + layer * DD;
    const float* bl  = lnb + layer * DD;

    // ---- phase 1: row sums of x (mask source)
    for (int r = wv; r < LQ; r += 8) {
      float s = 0.f;
      #pragma unroll
      for (int t = 0; t < 4; ++t) {
        int cc = lane + 64 * t;
        if (cc < DD) s += xs[r * XP + cc];
      }
      s = wave_sum(s);
      if (lane == 0) rowsum[r] = s;
    }

    // ---- phase 2: Q, K, V projections (V written transposed into v_T)
    matmul_mfma(xs, wq,  bql, q_s, XP, true, false, wv, lane);
    matmul_mfma(xs, wk,  bkl, k_s, KP, true, false, wv, lane);
    matmul_mfma(xs, wvv, bvl, v_T, VTP, true, true,  wv, lane);
    __syncthreads();

    // ---- phase 3: S = Q K^T via MFMA (B-frag of K^T == A-frag of K)
    f32x4 s0 = (f32x4)0.0f, s1 = (f32x4)0.0f;
    {
      const int mt = wv >> 1;
      int qr = mt * 16 + c;          if (qr >= LQ) qr = 0;
      const int ntk0 = (wv & 1) * 2;
      int kr0 = (ntk0 + 0) * 16 + c; if (kr0 >= LQ) kr0 = 0;
      int kr1 = (ntk0 + 1) * 16 + c; if (kr1 >= LQ) kr1 = 0;
      const float* qrow  = q_s + qr * XP;
      const float* krow0 = k_s + kr0 * KP;
      const float* krow1 = k_s + kr1 * KP;
      #pragma unroll 1
      for (int kt = 0; kt < KT; ++kt) {
        const int k0 = kt * 32 + g * 8;
        s16x8 qh = (s16x8)0, ql = (s16x8)0;
        s16x8 ah = (s16x8)0, al = (s16x8)0;
        s16x8 bh = (s16x8)0, bl2 = (s16x8)0;
        if (k0 < DD) {
          pack8(qrow  + k0, qh, ql);
          pack8(krow0 + k0, ah, al);
          pack8(krow1 + k0, bh, bl2);
        }
        s0 = __builtin_amdgcn_mfma_f32_16x16x32_bf16(qh, ah, s0, 0, 0, 0);
        s0 = __builtin_amdgcn_mfma_f32_16x16x32_bf16(ql, ah, s0, 0, 0, 0);
        s0 = __builtin_amdgcn_mfma_f32_16x16x32_bf16(qh, al, s0, 0, 0, 0);
        s1 = __builtin_amdgcn_mfma_f32_16x16x32_bf16(qh, bh, s1, 0, 0, 0);
        s1 = __builtin_amdgcn_mfma_f32_16x16x32_bf16(ql, bh, s1, 0, 0, 0);
        s1 = __builtin_amdgcn_mfma_f32_16x16x32_bf16(qh, bl2, s1, 0, 0, 0);
      }
    }
    __syncthreads();   // all Q/K reads done -> q_s reusable for S

    // ---- phase 4: write S (scaled + key-masked) into q_s (stride SP)
    {
      const int mt = wv >> 1;
      const int ntk0 = (wv & 1) * 2;
      #pragma unroll
      for (int t = 0; t < 2; ++t) {
        int j = (ntk0 + t) * 16 + c;
        f32x4 sa = t ? s1 : s0;
        bool km = (j < LQ) && (rowsum[j] != 0.0f);
        #pragma unroll
        for (int q = 0; q < 4; ++q) {
          int qi = mt * 16 + g * 4 + q;
          if (qi < LQ) q_s[qi * SP + j] = km ? sa[q] * SCALE : NEGC;
        }
      }
    }
    __syncthreads();

    // ---- phase 5: softmax rows (P written back, cols >=50 zeroed)
    for (int r = wv; r < LQ; r += 8) {
      float sm = -INFINITY;
      if (lane < LQ) sm = q_s[r * SP + lane];
      float m = wave_max(sm);
      float e = (lane < LQ) ? expf(sm - m) : 0.0f;
      float ssum = wave_sum(e);
      float qm = (rowsum[r] == 0.0f) ? 0.0f : 1.0f;
      q_s[r * SP + lane] = e / ssum * qm;
    }
    __syncthreads();

    // ---- phase 6: out^T = V^T @ P^T via MFMA; residual add into xs
    {
      s16x8 pbh[4][2], pbl[4][2];
      #pragma unroll
      for (int nt = 0; nt < 4; ++nt) {
        int pr = nt * 16 + c; if (pr >= LQ) pr = 0;
        const float* prow = q_s + pr * SP;
        #pragma unroll
        for (int kt = 0; kt < 2; ++kt)
          pack8(prow + kt * 32 + g * 8, pbh[nt][kt], pbl[nt][kt]);
      }
      #pragma unroll
      for (int mi = 0; mi < 2; ++mi) {
        int mt = wv + 8 * mi;
        if (mt < 13) {
          f32x4 pacc[4];
          #pragma unroll
          for (int nt = 0; nt < 4; ++nt) pacc[nt] = (f32x4)0.0f;
          int vr = mt * 16 + c; if (vr >= DD) vr = DD - 1;
          #pragma unroll
          for (int kt = 0; kt < 2; ++kt) {
            int k0 = kt * 32 + g * 8;
            s16x8 vh, vl;
            pack8_mask(v_T + vr * VTP + k0, k0, vh, vl);
            #pragma unroll
            for (int nt = 0; nt < 4; ++nt) {
              pacc[nt] = __builtin_amdgcn_mfma_f32_16x16x32_bf16(vh, pbh[nt][kt], pacc[nt], 0, 0, 0);
              pacc[nt] = __builtin_amdgcn_mfma_f32_16x16x32_bf16(vl, pbh[nt][kt], pacc[nt], 0, 0, 0);
              pacc[nt] = __builtin_amdgcn_mfma_f32_16x16x32_bf16(vh, pbl[nt][kt], pacc[nt], 0, 0, 0);
            }
          }
          #pragma unroll
          for (int nt = 0; nt < 4; ++nt) {
            int q = nt * 16 + c;
            if (q < LQ) {
              #pragma unroll
              for (int reg = 0; reg < 4; ++reg) {
                int d = mt * 16 + g * 4 + reg;
                if (d < DD) xs[q * XP + d] += pacc[nt][reg];
              }
            }
          }
        }
      }
    }
    __syncthreads();

    // ---- phase 7/8: FFN
    matmul_mfma(xs,  w1, b1l, q_s, XP, true,  false, wv, lane);
    __syncthreads();
    matmul_mfma(q_s, w2, b2l, k_s, KP, false, false, wv, lane);
    __syncthreads();

    // ---- phase 9: LayerNorm(h2)*g + b + x -> xs
    for (int r = wv; r < LQ; r += 8) {
      int c0 = lane, c1 = lane + 64, c2 = lane + 128, c3 = lane + 192;
      float h0 = k_s[r * KP + c0];
      float h1 = k_s[r * KP + c1];
      float h2 = k_s[r * KP + c2];
      float h3 = (c3 < DD) ? k_s[r * KP + c3] : 0.f;
      float mu = wave_sum(h0 + h1 + h2 + h3) * (1.0f / 200.0f);
      float d0 = h0 - mu, d1 = h1 - mu, d2 = h2 - mu;
      float d3 = (c3 < DD) ? (h3 - mu) : 0.f;
      float var = wave_sum(d0 * d0 + d1 * d1 + d2 * d2 + d3 * d3) * (1.0f / 200.0f);
      float inv = 1.0f / sqrtf(var + 1e-8f);
      xs[r * XP + c0] = d0 * inv * gl[c0] + bl[c0] + xs[r * XP + c0];
      xs[r * XP + c1] = d1 * inv * gl[c1] + bl[c1] + xs[r * XP + c1];
      xs[r * XP + c2] = d2 * inv * gl[c2] + bl[c2] + xs[r * XP + c2];
      if (c3 < DD)
        xs[r * XP + c3] = d3 * inv * gl[c3] + bl[c3] + xs[r * XP + c3];
    }
    __syncthreads();
  }

  // ---- write result
  for (int o2 = tid; o2 < LQ * 100; o2 += NT) {
    int r = o2 / 100, c2 = o2 % 100;
    *(float2*)(out + ((size_t)b * LQ + r) * DD + 2 * c2) =
        *(const float2*)(xs + r * XP + 2 * c2);
  }
}

extern "C" void kernel_launch(void* const* d_in, const int* in_sizes, int n_in,
                              void* d_out, int out_size, void* d_ws, size_t ws_size,
                              hipStream_t stream) {
  const int*   tokens = (const int*)  d_in[0];
  const float* emb    = (const float*)d_in[1];
  const float* Wq     = (const float*)d_in[2];
  const float* bq     = (const float*)d_in[3];
  const float* Wk     = (const float*)d_in[4];
  const float* bk     = (const float*)d_in[5];
  const float* Wv     = (const float*)d_in[6];
  const float* bv     = (const float*)d_in[7];
  const float* W1     = (const float*)d_in[8];
  const float* b1     = (const float*)d_in[9];
  const float* W2     = (const float*)d_in[10];
  const float* b2     = (const float*)d_in[11];
  const float* lng    = (const float*)d_in[12];
  const float* lnb    = (const float*)d_in[13];
  float* out = (float*)d_out;
  unsigned short* wbuf = (unsigned short*)d_ws;   // 15 * 200704 B = 2.87 MB

  hipLaunchKernelGGL(swizzle_w, dim3(15 * KT * NTL), dim3(64), 0, stream,
                     Wq, Wk, Wv, W1, W2, wbuf);

  const int B = in_sizes[0] / LQ;   // 4096
  hipLaunchKernelGGL(transformer_kernel, dim3(B), dim3(NT), 0, stream,
                     tokens, emb, wbuf, bq, bk, bv, b1, b2, lng, lnb, out);
}

// Round 5
// 1979.018 us; speedup vs baseline: 3.2804x; 1.3569x over previous
//
#include <hip/hip_runtime.h>
#include <math.h>

#define LQ 50
#define DD 200
#define NBLK 3
#define NT 512

#define KT 7
#define NTL 14
#define MAT_U (KT * NTL * 128)   // s16x8 units per matrix

#define APS 408   // pair-buffer row stride (shorts): 25 chunks*16 + 8 pad (2-way banks)
#define VTS 72    // v_T row stride (shorts): 8 chunks hi-only + pad (2-way)
#define PS  136   // P row stride (shorts): 8 chunks + pad (2-way)
#define SS  64    // S row stride (floats)

#define NEGC (-4294967295.0f)
#define SCALE 0.07071067811865475f

typedef __attribute__((ext_vector_type(4))) float f32x4;
typedef __attribute__((ext_vector_type(8))) short s16x8;

__device__ __forceinline__ unsigned short bf16_rne(float x) {
  unsigned u = __float_as_uint(x);
  unsigned r = u + 0x7FFF + ((u >> 16) & 1);
  return (unsigned short)(r >> 16);
}
__device__ __forceinline__ float bf16_f(unsigned short h) {
  return __uint_as_float((unsigned)h << 16);
}
__device__ __forceinline__ void splitf(float x, short& h, short& l) {
  unsigned short hh = bf16_rne(x);
  h = (short)hh;
  l = (short)bf16_rne(x - bf16_f(hh));
}
__device__ __forceinline__ float joinf(short h, short l) {
  return bf16_f((unsigned short)h) + bf16_f((unsigned short)l);
}

__device__ __forceinline__ float wave_sum(float v) {
  #pragma unroll
  for (int off = 32; off > 0; off >>= 1) v += __shfl_xor(v, off, 64);
  return v;
}
__device__ __forceinline__ float wave_max(float v) {
  #pragma unroll
  for (int off = 32; off > 0; off >>= 1) v = fmaxf(v, __shfl_xor(v, off, 64));
  return v;
}

// ---------------- pre-swizzle: W f32 [DD][DD] -> bf16 hi/lo fragment chunks ----
// chunk layout: [mat][kt][nt][h/l][lane][8 bf16]; slot k-map: k = kt*32 + (lane>>4)*8 + j
__global__ __launch_bounds__(64)
void swizzle_w(const float* __restrict__ Wq, const float* __restrict__ Wk,
               const float* __restrict__ Wv, const float* __restrict__ W1,
               const float* __restrict__ W2, unsigned short* __restrict__ wbuf)
{
  int t = blockIdx.x;             // 15*KT*NTL blocks
  int nt = t % NTL; t /= NTL;
  int kt = t % KT;  t /= KT;
  int mat = t;
  int layer = mat / 5, which = mat % 5;
  const float* W;
  switch (which) {
    case 0: W = Wq; break;
    case 1: W = Wk; break;
    case 2: W = Wv; break;
    case 3: W = W1; break;
    default: W = W2; break;
  }
  W += (size_t)layer * DD * DD;

  const int l = threadIdx.x;
  const int g = l >> 4, c = l & 15;
  const int n = nt * 16 + c;
  s16x8 vh, vl;
  #pragma unroll
  for (int j = 0; j < 8; ++j) {
    int k = kt * 32 + g * 8 + j;
    float w = (k < DD && n < DD) ? W[k * DD + n] : 0.0f;
    unsigned short h = bf16_rne(w);
    unsigned short lo = bf16_rne(w - bf16_f(h));
    vh[j] = (short)h;
    vl[j] = (short)lo;
  }
  size_t base = ((size_t)(mat * KT * NTL + kt * NTL + nt) * 2) * 512 + l * 8;
  *(s16x8*)(wbuf + base)       = vh;
  *(s16x8*)(wbuf + base + 512) = vl;
}

// ---------------- MFMA matmul over pair-format A, wbuf B --------------------
// MODE 0: dst = pair buffer (relu). MODE 1: dst = v_T hi-only transposed (relu,
// zero rows>=LQ). MODE 2: dst = f32 [LQ][DD] (no relu).
// Wave wv owns n-tiles {wv, wv+8} (wv+8 only if <13) x all 4 m-tiles.
template <int MODE>
__device__ __forceinline__ void big_matmul(
    const short* __restrict__ srcp, const s16x8* __restrict__ wt,
    const float* __restrict__ bias, short* __restrict__ dstp,
    float* __restrict__ dstf, int wv, int lane)
{
  const int g = lane >> 4, c = lane & 15;
  const int n1 = wv, n2 = wv + 8;
  const bool has2 = (n2 < 13);

  const short* arow[4];
  #pragma unroll
  for (int m = 0; m < 4; ++m) {
    int r = m * 16 + c;
    if (r >= LQ) r = 0;               // clamp: garbage confined to skipped rows
    arow[m] = srcp + r * APS;
  }

  f32x4 acc0[4], acc1[4];
  #pragma unroll
  for (int m = 0; m < 4; ++m) { acc0[m] = (f32x4)0.f; acc1[m] = (f32x4)0.f; }

  const s16x8* p1 = wt + n1 * 128 + lane;
  s16x8 b1h = p1[0], b1l = p1[64];
  s16x8 b2h = (s16x8)0, b2l = (s16x8)0;
  if (has2) { const s16x8* p2 = wt + n2 * 128 + lane; b2h = p2[0]; b2l = p2[64]; }

  #pragma unroll 1
  for (int kt = 0; kt < KT; ++kt) {
    // prefetch next-kt B fragments
    s16x8 x1h = (s16x8)0, x1l = (s16x8)0, x2h = (s16x8)0, x2l = (s16x8)0;
    if (kt + 1 < KT) {
      const s16x8* q1 = wt + ((kt + 1) * NTL + n1) * 128 + lane;
      x1h = q1[0]; x1l = q1[64];
      if (has2) {
        const s16x8* q2 = wt + ((kt + 1) * NTL + n2) * 128 + lane;
        x2h = q2[0]; x2l = q2[64];
      }
    }
    const int ch = kt * 4 + g;
    s16x8 ah[4], al[4];
    if (ch < 25) {
      #pragma unroll
      for (int m = 0; m < 4; ++m) {
        const short* ap = arow[m] + ch * 16;
        ah[m] = *(const s16x8*)ap;
        al[m] = *(const s16x8*)(ap + 8);
      }
    } else {
      #pragma unroll
      for (int m = 0; m < 4; ++m) { ah[m] = (s16x8)0; al[m] = (s16x8)0; }
    }
    #pragma unroll
    for (int m = 0; m < 4; ++m) {
      acc0[m] = __builtin_amdgcn_mfma_f32_16x16x32_bf16(ah[m], b1h, acc0[m], 0, 0, 0);
      acc0[m] = __builtin_amdgcn_mfma_f32_16x16x32_bf16(al[m], b1h, acc0[m], 0, 0, 0);
      acc0[m] = __builtin_amdgcn_mfma_f32_16x16x32_bf16(ah[m], b1l, acc0[m], 0, 0, 0);
    }
    if (has2) {
      #pragma unroll
      for (int m = 0; m < 4; ++m) {
        acc1[m] = __builtin_amdgcn_mfma_f32_16x16x32_bf16(ah[m], b2h, acc1[m], 0, 0, 0);
        acc1[m] = __builtin_amdgcn_mfma_f32_16x16x32_bf16(al[m], b2h, acc1[m], 0, 0, 0);
        acc1[m] = __builtin_amdgcn_mfma_f32_16x16x32_bf16(ah[m], b2l, acc1[m], 0, 0, 0);
      }
    }
    b1h = x1h; b1l = x1l; b2h = x2h; b2l = x2l;
  }

  // epilogue: C map col = lane&15 (of n-tile), row = (lane>>4)*4 + reg
  #pragma unroll
  for (int t = 0; t < 2; ++t) {
    const int nt = t ? n2 : n1;
    const int col = nt * 16 + c;
    if (col < DD) {                     // also naturally skips inactive n2
      const float bv = bias[col];
      #pragma unroll
      for (int m = 0; m < 4; ++m) {
        #pragma unroll
        for (int q = 0; q < 4; ++q) {
          const int r = m * 16 + g * 4 + q;
          float v = (t ? acc1[m][q] : acc0[m][q]) + bv;
          if (MODE == 0) {
            if (r < LQ) {
              v = fmaxf(v, 0.f);
              short h, l; splitf(v, h, l);
              short* hp = dstp + r * APS + (col >> 3) * 16 + (col & 7);
              hp[0] = h; hp[8] = l;
            }
          } else if (MODE == 1) {
            float vv = (r < LQ) ? fmaxf(v, 0.f) : 0.f;   // zero pad rows j>=50
            dstp[col * VTS + (r >> 3) * 8 + (r & 7)] = (short)bf16_rne(vv);
          } else {
            if (r < LQ) dstf[r * DD + col] = v;
          }
        }
      }
    }
  }
}

__global__ __launch_bounds__(NT)
void transformer_kernel(const int* __restrict__ tokens,
                        const float* __restrict__ emb,
                        const unsigned short* __restrict__ wbuf,
                        const float* __restrict__ bq, const float* __restrict__ bk,
                        const float* __restrict__ bv, const float* __restrict__ b1,
                        const float* __restrict__ b2,
                        const float* __restrict__ lng, const float* __restrict__ lnb,
                        float* __restrict__ out)
{
  __shared__ __align__(16) short xs_p[LQ * APS];   // residual pair     40800 B
  __shared__ __align__(16) short q_p [LQ * APS];   // Q / S+P / h1      40800 B
  __shared__ __align__(16) short k_p [LQ * APS];   // K / h2(f32)       40800 B
  __shared__ __align__(16) short vt_p[DD * VTS];   // V^T hi-only       28800 B
  __shared__ float rowsum[52];

  float* Sf  = (float*)q_p;          // S f32 [50][64] at q_p bytes 0..12800
  short* Pp  = q_p + 8192;           // P pair [50][PS] at byte 16384..29984
  float* h2f = (float*)k_p;          // h2 f32 [50][200]

  const int b    = blockIdx.x;
  const int tid  = threadIdx.x;
  const int lane = tid & 63;
  const int wv   = tid >> 6;
  const int g    = lane >> 4, c = lane & 15;

  // ---- embedding gather -> xs pair (exact zeros preserved)
  for (int o = tid; o < LQ * 25; o += NT) {
    int r = o / 25, ch = o % 25;
    int tok = tokens[b * LQ + r];
    const float* ep = emb + (size_t)tok * DD + ch * 8;
    float4 a0 = *(const float4*)ep;
    float4 a1 = *(const float4*)(ep + 4);
    float xv[8] = {a0.x, a0.y, a0.z, a0.w, a1.x, a1.y, a1.z, a1.w};
    s16x8 hh, ll;
    #pragma unroll
    for (int j = 0; j < 8; ++j) { short h, l; splitf(xv[j], h, l); hh[j] = h; ll[j] = l; }
    short* dp = xs_p + r * APS + ch * 16;
    *(s16x8*)dp = hh;
    *(s16x8*)(dp + 8) = ll;
  }
  __syncthreads();

  for (int layer = 0; layer < NBLK; ++layer) {
    const s16x8* wq  = (const s16x8*)wbuf + (size_t)(layer * 5 + 0) * MAT_U;
    const s16x8* wk  = (const s16x8*)wbuf + (size_t)(layer * 5 + 1) * MAT_U;
    const s16x8* wvv = (const s16x8*)wbuf + (size_t)(layer * 5 + 2) * MAT_U;
    const s16x8* w1  = (const s16x8*)wbuf + (size_t)(layer * 5 + 3) * MAT_U;
    const s16x8* w2  = (const s16x8*)wbuf + (size_t)(layer * 5 + 4) * MAT_U;
    const float* bql = bq + layer * DD;
    const float* bkl = bk + layer * DD;
    const float* bvl = bv + layer * DD;
    const float* b1l = b1 + layer * DD;
    const float* b2l = b2 + layer * DD;
    const float* gl  = lng + layer * DD;
    const float* bl  = lnb + layer * DD;

    // ---- phase 1: row sums of x (mask source; exact for all-zero rows)
    for (int r = wv; r < LQ; r += 8) {
      float s = 0.f;
      #pragma unroll
      for (int t = 0; t < 4; ++t) {
        int cc = lane + 64 * t;
        if (cc < DD) {
          const short* p = xs_p + r * APS + (cc >> 3) * 16 + (cc & 7);
          s += joinf(p[0], p[8]);
        }
      }
      s = wave_sum(s);
      if (lane == 0) rowsum[r] = s;
    }

    // ---- phase 2: Q, K, V projections (each weight fragment read ONCE/block)
    big_matmul<0>(xs_p, wq,  bql, q_p,  nullptr, wv, lane);
    big_matmul<0>(xs_p, wk,  bkl, k_p,  nullptr, wv, lane);
    big_matmul<1>(xs_p, wvv, bvl, vt_p, nullptr, wv, lane);
    __syncthreads();

    // ---- phase 3: S = Q K^T via MFMA (all-LDS)
    f32x4 s0 = (f32x4)0.f, s1 = (f32x4)0.f;
    {
      const int mt = wv >> 1;
      const int nk0 = (wv & 1) * 2;
      int qr = mt * 16 + c;        if (qr >= LQ) qr = 0;
      int kj0 = nk0 * 16 + c;      if (kj0 >= LQ) kj0 = 0;
      int kj1 = (nk0 + 1) * 16 + c; if (kj1 >= LQ) kj1 = 0;
      const short* qrow = q_p + qr * APS;
      const short* k0r  = k_p + kj0 * APS;
      const short* k1r  = k_p + kj1 * APS;
      #pragma unroll 1
      for (int kt = 0; kt < KT; ++kt) {
        const int ch = kt * 4 + g;
        s16x8 qh = (s16x8)0, ql = (s16x8)0;
        s16x8 kh0 = (s16x8)0, kl0 = (s16x8)0, kh1 = (s16x8)0, kl1 = (s16x8)0;
        if (ch < 25) {
          qh  = *(const s16x8*)(qrow + ch * 16); ql  = *(const s16x8*)(qrow + ch * 16 + 8);
          kh0 = *(const s16x8*)(k0r + ch * 16);  kl0 = *(const s16x8*)(k0r + ch * 16 + 8);
          kh1 = *(const s16x8*)(k1r + ch * 16);  kl1 = *(const s16x8*)(k1r + ch * 16 + 8);
        }
        s0 = __builtin_amdgcn_mfma_f32_16x16x32_bf16(qh, kh0, s0, 0, 0, 0);
        s0 = __builtin_amdgcn_mfma_f32_16x16x32_bf16(ql, kh0, s0, 0, 0, 0);
        s0 = __builtin_amdgcn_mfma_f32_16x16x32_bf16(qh, kl0, s0, 0, 0, 0);
        s1 = __builtin_amdgcn_mfma_f32_16x16x32_bf16(qh, kh1, s1, 0, 0, 0);
        s1 = __builtin_amdgcn_mfma_f32_16x16x32_bf16(ql, kh1, s1, 0, 0, 0);
        s1 = __builtin_amdgcn_mfma_f32_16x16x32_bf16(qh, kl1, s1, 0, 0, 0);
      }
    }
    __syncthreads();   // all q_p reads done -> S may overwrite

    // ---- phase 4: write S (scaled + key-masked) into Sf
    {
      const int mt = wv >> 1;
      const int nk0 = (wv & 1) * 2;
      #pragma unroll
      for (int t = 0; t < 2; ++t) {
        const int j = (nk0 + t) * 16 + c;
        const f32x4 sa = t ? s1 : s0;
        const bool km = (j < LQ) && (rowsum[j] != 0.0f);
        #pragma unroll
        for (int q = 0; q < 4; ++q) {
          const int qi = mt * 16 + g * 4 + q;
          if (qi < LQ) Sf[qi * SS + j] = km ? sa[q] * SCALE : NEGC;
        }
      }
    }
    __syncthreads();

    // ---- phase 5: softmax rows -> P pair (rows < 50; cols >= 50 get zeros)
    for (int r = wv; r < LQ; r += 8) {
      float sm = -INFINITY;
      if (lane < LQ) sm = Sf[r * SS + lane];
      float m = wave_max(sm);
      float e = (lane < LQ) ? expf(sm - m) : 0.0f;
      float ssum = wave_sum(e);
      float qm = (rowsum[r] == 0.0f) ? 0.0f : 1.0f;
      float a = e / ssum * qm;
      short h, l; splitf(a, h, l);
      short* pp = Pp + r * PS + (lane >> 3) * 16 + (lane & 7);
      pp[0] = h; pp[8] = l;
    }
    __syncthreads();

    // ---- phase 6: out^T = V^T @ P^T via MFMA; residual RMW into xs pair
    {
      s16x8 pbh[4][2], pbl[4][2];
      #pragma unroll
      for (int nq = 0; nq < 4; ++nq) {
        int pr = nq * 16 + c; if (pr >= LQ) pr = 0;
        const short* pp = Pp + pr * PS;
        #pragma unroll
        for (int kt = 0; kt < 2; ++kt) {
          pbh[nq][kt] = *(const s16x8*)(pp + (kt * 4 + g) * 16);
          pbl[nq][kt] = *(const s16x8*)(pp + (kt * 4 + g) * 16 + 8);
        }
      }
      #pragma unroll
      for (int mi = 0; mi < 2; ++mi) {
        const int mt = wv + 8 * mi;
        if (mt < 13) {
          f32x4 pa[4];
          #pragma unroll
          for (int nq = 0; nq < 4; ++nq) pa[nq] = (f32x4)0.f;
          int vr = mt * 16 + c; if (vr >= DD) vr = 0;
          const short* vrow = vt_p + vr * VTS;
          #pragma unroll
          for (int kt = 0; kt < 2; ++kt) {
            s16x8 vh = *(const s16x8*)(vrow + (kt * 4 + g) * 8);
            #pragma unroll
            for (int nq = 0; nq < 4; ++nq) {
              pa[nq] = __builtin_amdgcn_mfma_f32_16x16x32_bf16(vh, pbh[nq][kt], pa[nq], 0, 0, 0);
              pa[nq] = __builtin_amdgcn_mfma_f32_16x16x32_bf16(vh, pbl[nq][kt], pa[nq], 0, 0, 0);
            }
          }
          #pragma unroll
          for (int nq = 0; nq < 4; ++nq) {
            const int qq = nq * 16 + c;
            if (qq < LQ) {
              #pragma unroll
              for (int reg = 0; reg < 4; ++reg) {
                const int d = mt * 16 + g * 4 + reg;
                if (d < DD) {
                  short* hp = xs_p + qq * APS + (d >> 3) * 16 + (d & 7);
                  float f = joinf(hp[0], hp[8]) + pa[nq][reg];
                  short h, l; splitf(f, h, l);
                  hp[0] = h; hp[8] = l;
                }
              }
            }
          }
        }
      }
    }
    __syncthreads();

    // ---- phase 7/8: FFN
    big_matmul<0>(xs_p, w1, b1l, q_p, nullptr, wv, lane);
    __syncthreads();
    big_matmul<2>(q_p, w2, b2l, nullptr, h2f, wv, lane);
    __syncthreads();

    // ---- phase 9: LayerNorm(h2)*g + b + x -> xs pair
    for (int r = wv; r < LQ; r += 8) {
      float hv[4];
      #pragma unroll
      for (int t = 0; t < 4; ++t) {
        int cc = lane + 64 * t;
        hv[t] = (cc < DD) ? h2f[r * DD + cc] : 0.f;
      }
      float mu = wave_sum(hv[0] + hv[1] + hv[2] + hv[3]) * (1.0f / 200.0f);
      float d0 = hv[0] - mu, d1 = hv[1] - mu, d2 = hv[2] - mu;
      float d3 = (lane + 192 < DD) ? (hv[3] - mu) : 0.f;
      float var = wave_sum(d0 * d0 + d1 * d1 + d2 * d2 + d3 * d3) * (1.0f / 200.0f);
      float inv = 1.0f / sqrtf(var + 1e-8f);
      float dd4[4] = {d0, d1, d2, d3};
      #pragma unroll
      for (int t = 0; t < 4; ++t) {
        int cc = lane + 64 * t;
        if (cc < DD) {
          short* hp = xs_p + r * APS + (cc >> 3) * 16 + (cc & 7);
          float nv = dd4[t] * inv * gl[cc] + bl[cc] + joinf(hp[0], hp[8]);
          short h, l; splitf(nv, h, l);
          hp[0] = h; hp[8] = l;
        }
      }
    }
    __syncthreads();
  }

  // ---- write result
  for (int o = tid; o < LQ * 25; o += NT) {
    int r = o / 25, ch = o % 25;
    const short* sp = xs_p + r * APS + ch * 16;
    s16x8 hh = *(const s16x8*)sp;
    s16x8 ll = *(const s16x8*)(sp + 8);
    float4 o0, o1;
    o0.x = joinf(hh[0], ll[0]); o0.y = joinf(hh[1], ll[1]);
    o0.z = joinf(hh[2], ll[2]); o0.w = joinf(hh[3], ll[3]);
    o1.x = joinf(hh[4], ll[4]); o1.y = joinf(hh[5], ll[5]);
    o1.z = joinf(hh[6], ll[6]); o1.w = joinf(hh[7], ll[7]);
    float* op = out + ((size_t)b * LQ + r) * DD + ch * 8;
    *(float4*)op = o0;
    *(float4*)(op + 4) = o1;
  }
}

extern "C" void kernel_launch(void* const* d_in, const int* in_sizes, int n_in,
                              void* d_out, int out_size, void* d_ws, size_t ws_size,
                              hipStream_t stream) {
  const int*   tokens = (const int*)  d_in[0];
  const float* emb    = (const float*)d_in[1];
  const float* Wq     = (const float*)d_in[2];
  const float* bq     = (const float*)d_in[3];
  const float* Wk     = (const float*)d_in[4];
  const float* bk     = (const float*)d_in[5];
  const float* Wv     = (const float*)d_in[6];
  const float* bv     = (const float*)d_in[7];
  const float* W1     = (const float*)d_in[8];
  const float* b1     = (const float*)d_in[9];
  const float* W2     = (const float*)d_in[10];
  const float* b2     = (const float*)d_in[11];
  const float* lng    = (const float*)d_in[12];
  const float* lnb    = (const float*)d_in[13];
  float* out = (float*)d_out;
  unsigned short* wbuf = (unsigned short*)d_ws;   // 15 * 200704 B = 2.87 MB

  hipLaunchKernelGGL(swizzle_w, dim3(15 * KT * NTL), dim3(64), 0, stream,
                     Wq, Wk, Wv, W1, W2, wbuf);

  const int B = in_sizes[0] / LQ;   // 4096
  hipLaunchKernelGGL(transformer_kernel, dim3(B), dim3(NT), 0, stream,
                     tokens, emb, wbuf, bq, bk, bv, b1, b2, lng, lnb, out);
}

// Round 7
// 1887.263 us; speedup vs baseline: 3.4399x; 1.0486x over previous
//
#include <hip/hip_runtime.h>
#include <hip/hip_bf16.h>
#include <math.h>

#define LQ 50
#define DD 200
#define NBLK 3
#define NT 512

#define KT 7
#define NTL 14
#define MAT_U (KT * NTL * 128)   // s16x8 units per matrix

#define APS 408   // pair-buffer row stride (shorts)
#define VTS 72    // v_T row stride (shorts)
#define PS  136   // P row stride (shorts)
#define SS  64    // S row stride (floats)

#define NEGC (-4294967295.0f)
#define SCALE 0.07071067811865475f

typedef __attribute__((ext_vector_type(4))) float f32x4;
typedef __attribute__((ext_vector_type(8))) short s16x8;

// cold-path (swizzle kernel) manual split
__device__ __forceinline__ unsigned short bf16_rne(float x) {
  unsigned u = __float_as_uint(x);
  unsigned r = u + 0x7FFF + ((u >> 16) & 1);
  return (unsigned short)(r >> 16);
}
__device__ __forceinline__ float bf16_f(unsigned short h) {
  return __uint_as_float((unsigned)h << 16);
}

// hot-path: hardware cvt based split/join
__device__ __forceinline__ void splitf(float x, short& h, short& l) {
  __hip_bfloat16 bh = __float2bfloat16(x);
  float hf = __bfloat162float(bh);
  __hip_bfloat16 bl = __float2bfloat16(x - hf);
  h = (short)__builtin_bit_cast(unsigned short, bh);
  l = (short)__builtin_bit_cast(unsigned short, bl);
}
__device__ __forceinline__ unsigned short bfbits(float x) {
  __hip_bfloat16 bh = __float2bfloat16(x);
  return __builtin_bit_cast(unsigned short, bh);
}
__device__ __forceinline__ float joinf(short h, short l) {
  return __bfloat162float(__builtin_bit_cast(__hip_bfloat16, (unsigned short)h)) +
         __bfloat162float(__builtin_bit_cast(__hip_bfloat16, (unsigned short)l));
}

__device__ __forceinline__ float wave_sum(float v) {
  #pragma unroll
  for (int off = 32; off > 0; off >>= 1) v += __shfl_xor(v, off, 64);
  return v;
}
__device__ __forceinline__ float wave_max(float v) {
  #pragma unroll
  for (int off = 32; off > 0; off >>= 1) v = fmaxf(v, __shfl_xor(v, off, 64));
  return v;
}

// ---------------- pre-swizzle: W f32 [DD][DD] -> bf16 hi/lo fragment chunks ----
__global__ __launch_bounds__(64)
void swizzle_w(const float* __restrict__ Wq, const float* __restrict__ Wk,
               const float* __restrict__ Wv, const float* __restrict__ W1,
               const float* __restrict__ W2, unsigned short* __restrict__ wbuf)
{
  int t = blockIdx.x;
  int nt = t % NTL; t /= NTL;
  int kt = t % KT;  t /= KT;
  int mat = t;
  int layer = mat / 5, which = mat % 5;
  const float* W;
  switch (which) {
    case 0: W = Wq; break;
    case 1: W = Wk; break;
    case 2: W = Wv; break;
    case 3: W = W1; break;
    default: W = W2; break;
  }
  W += (size_t)layer * DD * DD;

  const int l = threadIdx.x;
  const int g = l >> 4, c = l & 15;
  const int n = nt * 16 + c;
  s16x8 vh, vl;
  #pragma unroll
  for (int j = 0; j < 8; ++j) {
    int k = kt * 32 + g * 8 + j;
    float w = (k < DD && n < DD) ? W[k * DD + n] : 0.0f;
    unsigned short h = bf16_rne(w);
    unsigned short lo = bf16_rne(w - bf16_f(h));
    vh[j] = (short)h;
    vl[j] = (short)lo;
  }
  size_t base = ((size_t)(mat * KT * NTL + kt * NTL + nt) * 2) * 512 + l * 8;
  *(s16x8*)(wbuf + base)       = vh;
  *(s16x8*)(wbuf + base + 512) = vl;
}

// ---------------- MFMA matmul over pair-format A, wbuf B --------------------
// MODE 0: dst = pair buffer (relu). MODE 1: dst = v_T hi-only transposed (relu,
// zero rows>=LQ, packed b64 writes). MODE 2: dst = f32 [LQ][DD] (no relu).
template <int MODE>
__device__ __forceinline__ void big_matmul(
    const short* __restrict__ srcp, const s16x8* __restrict__ wt,
    const float* __restrict__ bias, short* __restrict__ dstp,
    float* __restrict__ dstf, int wv, int lane)
{
  const int g = lane >> 4, c = lane & 15;
  const int n1 = wv, n2 = wv + 8;
  const bool has2 = (n2 < 13);

  const short* arow[4];
  #pragma unroll
  for (int m = 0; m < 4; ++m) {
    int r = m * 16 + c;
    if (r >= LQ) r = 0;
    arow[m] = srcp + r * APS;
  }

  f32x4 acc0[4], acc1[4];
  #pragma unroll
  for (int m = 0; m < 4; ++m) { acc0[m] = (f32x4)0.f; acc1[m] = (f32x4)0.f; }

  const s16x8* p1 = wt + n1 * 128 + lane;
  s16x8 b1h = p1[0], b1l = p1[64];
  s16x8 b2h = (s16x8)0, b2l = (s16x8)0;
  if (has2) { const s16x8* p2 = wt + n2 * 128 + lane; b2h = p2[0]; b2l = p2[64]; }

  #pragma unroll 1
  for (int kt = 0; kt < KT; ++kt) {
    s16x8 x1h = (s16x8)0, x1l = (s16x8)0, x2h = (s16x8)0, x2l = (s16x8)0;
    if (kt + 1 < KT) {
      const s16x8* q1 = wt + ((kt + 1) * NTL + n1) * 128 + lane;
      x1h = q1[0]; x1l = q1[64];
      if (has2) {
        const s16x8* q2 = wt + ((kt + 1) * NTL + n2) * 128 + lane;
        x2h = q2[0]; x2l = q2[64];
      }
    }
    const int ch = kt * 4 + g;
    s16x8 ah[4], al[4];
    if (ch < 25) {
      #pragma unroll
      for (int m = 0; m < 4; ++m) {
        const short* ap = arow[m] + ch * 16;
        ah[m] = *(const s16x8*)ap;
        al[m] = *(const s16x8*)(ap + 8);
      }
    } else {
      #pragma unroll
      for (int m = 0; m < 4; ++m) { ah[m] = (s16x8)0; al[m] = (s16x8)0; }
    }
    #pragma unroll
    for (int m = 0; m < 4; ++m) {
      acc0[m] = __builtin_amdgcn_mfma_f32_16x16x32_bf16(ah[m], b1h, acc0[m], 0, 0, 0);
      acc0[m] = __builtin_amdgcn_mfma_f32_16x16x32_bf16(al[m], b1h, acc0[m], 0, 0, 0);
      acc0[m] = __builtin_amdgcn_mfma_f32_16x16x32_bf16(ah[m], b1l, acc0[m], 0, 0, 0);
    }
    if (has2) {
      #pragma unroll
      for (int m = 0; m < 4; ++m) {
        acc1[m] = __builtin_amdgcn_mfma_f32_16x16x32_bf16(ah[m], b2h, acc1[m], 0, 0, 0);
        acc1[m] = __builtin_amdgcn_mfma_f32_16x16x32_bf16(al[m], b2h, acc1[m], 0, 0, 0);
        acc1[m] = __builtin_amdgcn_mfma_f32_16x16x32_bf16(ah[m], b2l, acc1[m], 0, 0, 0);
      }
    }
    b1h = x1h; b1l = x1l; b2h = x2h; b2l = x2l;
  }

  #pragma unroll
  for (int t = 0; t < 2; ++t) {
    const int nt = t ? n2 : n1;
    const int col = nt * 16 + c;
    if (col < DD) {
      const float bv = bias[col];
      #pragma unroll
      for (int m = 0; m < 4; ++m) {
        const int rb = m * 16 + g * 4;
        if (MODE == 1) {
          float vv[4];
          #pragma unroll
          for (int q = 0; q < 4; ++q) {
            const int r = rb + q;
            float v = (t ? acc1[m][q] : acc0[m][q]) + bv;
            vv[q] = (r < LQ) ? fmaxf(v, 0.f) : 0.f;
          }
          unsigned u0 = (unsigned)bfbits(vv[0]) | ((unsigned)bfbits(vv[1]) << 16);
          unsigned u1 = (unsigned)bfbits(vv[2]) | ((unsigned)bfbits(vv[3]) << 16);
          uint2 pk; pk.x = u0; pk.y = u1;
          *(uint2*)(dstp + col * VTS + (rb >> 3) * 8 + (rb & 7)) = pk;
        } else {
          #pragma unroll
          for (int q = 0; q < 4; ++q) {
            const int r = rb + q;
            float v = (t ? acc1[m][q] : acc0[m][q]) + bv;
            if (MODE == 0) {
              if (r < LQ) {
                v = fmaxf(v, 0.f);
                short h, l; splitf(v, h, l);
                short* hp = dstp + r * APS + (col >> 3) * 16 + (col & 7);
                hp[0] = h; hp[8] = l;
              }
            } else {
              if (r < LQ) dstf[r * DD + col] = v;
            }
          }
        }
      }
    }
  }
}

__global__ __launch_bounds__(NT)
void transformer_kernel(const int* __restrict__ tokens,
                        const float* __restrict__ emb,
                        const unsigned short* __restrict__ wbuf,
                        const float* __restrict__ bq, const float* __restrict__ bk,
                        const float* __restrict__ bv, const float* __restrict__ b1,
                        const float* __restrict__ b2,
                        const float* __restrict__ lng, const float* __restrict__ lnb,
                        float* __restrict__ out)
{
  __shared__ __align__(16) short xs_p[LQ * APS];   // residual pair     40800 B
  __shared__ __align__(16) short q_p [LQ * APS];   // Q / S+P / h1      40800 B
  __shared__ __align__(16) short k_p [LQ * APS];   // K / aout / h2     40800 B
  __shared__ __align__(16) short vt_p[DD * VTS];   // V^T hi-only       28800 B
  __shared__ float rowsum[52];

  float* Sf   = (float*)q_p;         // S f32 [50][64]
  short* Pp   = q_p + 8192;          // P pair [50][PS]
  float* aout = (float*)k_p;         // attn-out f32 [50][200]
  float* h2f  = (float*)k_p;         // h2 f32 [50][200]

  const int b    = blockIdx.x;
  const int tid  = threadIdx.x;
  const int lane = tid & 63;
  const int wv   = tid >> 6;
  const int g    = lane >> 4, c = lane & 15;

  // ---- embedding gather -> xs pair
  for (int o = tid; o < LQ * 25; o += NT) {
    int r = o / 25, ch = o % 25;
    int tok = tokens[b * LQ + r];
    const float* ep = emb + (size_t)tok * DD + ch * 8;
    float4 a0 = *(const float4*)ep;
    float4 a1 = *(const float4*)(ep + 4);
    float xv[8] = {a0.x, a0.y, a0.z, a0.w, a1.x, a1.y, a1.z, a1.w};
    s16x8 hh, ll;
    #pragma unroll
    for (int j = 0; j < 8; ++j) { short h, l; splitf(xv[j], h, l); hh[j] = h; ll[j] = l; }
    short* dp = xs_p + r * APS + ch * 16;
    *(s16x8*)dp = hh;
    *(s16x8*)(dp + 8) = ll;
  }
  __syncthreads();

  for (int layer = 0; layer < NBLK; ++layer) {
    const s16x8* wq  = (const s16x8*)wbuf + (size_t)(layer * 5 + 0) * MAT_U;
    const s16x8* wk  = (const s16x8*)wbuf + (size_t)(layer * 5 + 1) * MAT_U;
    const s16x8* wvv = (const s16x8*)wbuf + (size_t)(layer * 5 + 2) * MAT_U;
    const s16x8* w1  = (const s16x8*)wbuf + (size_t)(layer * 5 + 3) * MAT_U;
    const s16x8* w2  = (const s16x8*)wbuf + (size_t)(layer * 5 + 4) * MAT_U;
    const float* bql = bq + layer * DD;
    const float* bkl = bk + layer * DD;
    const float* bvl = bv + layer * DD;
    const float* b1l = b1 + layer * DD;
    const float* b2l = b2 + layer * DD;
    const float* gl  = lng + layer * DD;
    const float* bl  = lnb + layer * DD;

    // ---- phase 1: row sums of x (mask source)
    for (int r = wv; r < LQ; r += 8) {
      float s = 0.f;
      #pragma unroll
      for (int t = 0; t < 4; ++t) {
        int cc = lane + 64 * t;
        if (cc < DD) {
          const short* p = xs_p + r * APS + (cc >> 3) * 16 + (cc & 7);
          s += joinf(p[0], p[8]);
        }
      }
      s = wave_sum(s);
      if (lane == 0) rowsum[r] = s;
    }

    // ---- phase 2: Q, K, V projections
    big_matmul<0>(xs_p, wq,  bql, q_p,  nullptr, wv, lane);
    big_matmul<0>(xs_p, wk,  bkl, k_p,  nullptr, wv, lane);
    big_matmul<1>(xs_p, wvv, bvl, vt_p, nullptr, wv, lane);
    __syncthreads();

    // ---- phase 3: S = Q K^T via MFMA
    f32x4 s0 = (f32x4)0.f, s1 = (f32x4)0.f;
    {
      const int mt = wv >> 1;
      const int nk0 = (wv & 1) * 2;
      int qr = mt * 16 + c;         if (qr >= LQ) qr = 0;
      int kj0 = nk0 * 16 + c;       if (kj0 >= LQ) kj0 = 0;
      int kj1 = (nk0 + 1) * 16 + c; if (kj1 >= LQ) kj1 = 0;
      const short* qrow = q_p + qr * APS;
      const short* k0r  = k_p + kj0 * APS;
      const short* k1r  = k_p + kj1 * APS;
      #pragma unroll 1
      for (int kt = 0; kt < KT; ++kt) {
        const int ch = kt * 4 + g;
        s16x8 qh = (s16x8)0, ql = (s16x8)0;
        s16x8 kh0 = (s16x8)0, kl0 = (s16x8)0, kh1 = (s16x8)0, kl1 = (s16x8)0;
        if (ch < 25) {
          qh  = *(const s16x8*)(qrow + ch * 16); ql  = *(const s16x8*)(qrow + ch * 16 + 8);
          kh0 = *(const s16x8*)(k0r + ch * 16);  kl0 = *(const s16x8*)(k0r + ch * 16 + 8);
          kh1 = *(const s16x8*)(k1r + ch * 16);  kl1 = *(const s16x8*)(k1r + ch * 16 + 8);
        }
        s0 = __builtin_amdgcn_mfma_f32_16x16x32_bf16(qh, kh0, s0, 0, 0, 0);
        s0 = __builtin_amdgcn_mfma_f32_16x16x32_bf16(ql, kh0, s0, 0, 0, 0);
        s0 = __builtin_amdgcn_mfma_f32_16x16x32_bf16(qh, kl0, s0, 0, 0, 0);
        s1 = __builtin_amdgcn_mfma_f32_16x16x32_bf16(qh, kh1, s1, 0, 0, 0);
        s1 = __builtin_amdgcn_mfma_f32_16x16x32_bf16(ql, kh1, s1, 0, 0, 0);
        s1 = __builtin_amdgcn_mfma_f32_16x16x32_bf16(qh, kl1, s1, 0, 0, 0);
      }
    }
    __syncthreads();

    // ---- phase 4: write S (scaled + key-masked) into Sf
    {
      const int mt = wv >> 1;
      const int nk0 = (wv & 1) * 2;
      #pragma unroll
      for (int t = 0; t < 2; ++t) {
        const int j = (nk0 + t) * 16 + c;
        const f32x4 sa = t ? s1 : s0;
        const bool km = (j < LQ) && (rowsum[j] != 0.0f);
        #pragma unroll
        for (int q = 0; q < 4; ++q) {
          const int qi = mt * 16 + g * 4 + q;
          if (qi < LQ) Sf[qi * SS + j] = km ? sa[q] * SCALE : NEGC;
        }
      }
    }
    __syncthreads();

    // ---- phase 5: softmax rows -> P pair
    for (int r = wv; r < LQ; r += 8) {
      float sm = -INFINITY;
      if (lane < LQ) sm = Sf[r * SS + lane];
      float m = wave_max(sm);
      float e = (lane < LQ) ? __expf(sm - m) : 0.0f;
      float ssum = wave_sum(e);
      float qm = (rowsum[r] == 0.0f) ? 0.0f : 1.0f;
      float a = e / ssum * qm;
      short h, l; splitf(a, h, l);
      short* pp = Pp + r * PS + (lane >> 3) * 16 + (lane & 7);
      pp[0] = h; pp[8] = l;
    }
    __syncthreads();

    // ---- phase 6: out^T = V^T @ P^T -> aout f32 (in dead k_p), b128 writes
    {
      s16x8 pbh[4][2], pbl[4][2];
      #pragma unroll
      for (int nq = 0; nq < 4; ++nq) {
        int pr = nq * 16 + c; if (pr >= LQ) pr = 0;
        const short* pp = Pp + pr * PS;
        #pragma unroll
        for (int kt = 0; kt < 2; ++kt) {
          pbh[nq][kt] = *(const s16x8*)(pp + (kt * 4 + g) * 16);
          pbl[nq][kt] = *(const s16x8*)(pp + (kt * 4 + g) * 16 + 8);
        }
      }
      #pragma unroll
      for (int mi = 0; mi < 2; ++mi) {
        const int mt = wv + 8 * mi;
        if (mt < 13) {
          f32x4 pa[4];
          #pragma unroll
          for (int nq = 0; nq < 4; ++nq) pa[nq] = (f32x4)0.f;
          int vr = mt * 16 + c; if (vr >= DD) vr = 0;
          const short* vrow = vt_p + vr * VTS;
          #pragma unroll
          for (int kt = 0; kt < 2; ++kt) {
            s16x8 vh = *(const s16x8*)(vrow + (kt * 4 + g) * 8);
            #pragma unroll
            for (int nq = 0; nq < 4; ++nq) {
              pa[nq] = __builtin_amdgcn_mfma_f32_16x16x32_bf16(vh, pbh[nq][kt], pa[nq], 0, 0, 0);
              pa[nq] = __builtin_amdgcn_mfma_f32_16x16x32_bf16(vh, pbl[nq][kt], pa[nq], 0, 0, 0);
            }
          }
          // lane holds 4 consecutive d = mt*16+g*4.. for q = nq*16+c
          const int d0 = mt * 16 + g * 4;
          if (d0 + 3 < DD) {
            #pragma unroll
            for (int nq = 0; nq < 4; ++nq) {
              const int qq = nq * 16 + c;
              if (qq < LQ) {
                float4 w4; w4.x = pa[nq][0]; w4.y = pa[nq][1];
                w4.z = pa[nq][2]; w4.w = pa[nq][3];
                *(float4*)(aout + qq * 200 + d0) = w4;
              }
            }
          }
        }
      }
    }
    __syncthreads();

    // ---- phase 6b: vectorized merge  xs += aout
    for (int o = tid; o < LQ * 25; o += NT) {
      int r = o / 25, ch = o % 25;
      const float* ap = aout + r * 200 + ch * 8;
      float4 a0 = *(const float4*)ap;
      float4 a1 = *(const float4*)(ap + 4);
      float av[8] = {a0.x, a0.y, a0.z, a0.w, a1.x, a1.y, a1.z, a1.w};
      short* xp = xs_p + r * APS + ch * 16;
      s16x8 hh = *(const s16x8*)xp;
      s16x8 ll = *(const s16x8*)(xp + 8);
      #pragma unroll
      for (int j = 0; j < 8; ++j) {
        float f = joinf(hh[j], ll[j]) + av[j];
        short h, l; splitf(f, h, l);
        hh[j] = h; ll[j] = l;
      }
      *(s16x8*)xp = hh;
      *(s16x8*)(xp + 8) = ll;
    }
    __syncthreads();

    // ---- phase 7/8: FFN
    big_matmul<0>(xs_p, w1, b1l, q_p, nullptr, wv, lane);
    __syncthreads();
    big_matmul<2>(q_p, w2, b2l, nullptr, h2f, wv, lane);
    __syncthreads();

    // ---- phase 9: LayerNorm(h2)*g + b + x -> xs pair
    for (int r = wv; r < LQ; r += 8) {
      float hv[4];
      #pragma unroll
      for (int t = 0; t < 4; ++t) {
        int cc = lane + 64 * t;
        hv[t] = (cc < DD) ? h2f[r * DD + cc] : 0.f;
      }
      float mu = wave_sum(hv[0] + hv[1] + hv[2] + hv[3]) * (1.0f / 200.0f);
      float d0 = hv[0] - mu, d1 = hv[1] - mu, d2 = hv[2] - mu;
      float d3 = (lane + 192 < DD) ? (hv[3] - mu) : 0.f;
      float var = wave_sum(d0 * d0 + d1 * d1 + d2 * d2 + d3 * d3) * (1.0f / 200.0f);
      float inv = 1.0f / sqrtf(var + 1e-8f);
      float dd4[4] = {d0, d1, d2, d3};
      #pragma unroll
      for (int t = 0; t < 4; ++t) {
        int cc = lane + 64 * t;
        if (cc < DD) {
          short* hp = xs_p + r * APS + (cc >> 3) * 16 + (cc & 7);
          float nv = dd4[t] * inv * gl[cc] + bl[cc] + joinf(hp[0], hp[8]);
          short h, l; splitf(nv, h, l);
          hp[0] = h; hp[8] = l;
        }
      }
    }
    __syncthreads();
  }

  // ---- write result
  for (int o = tid; o < LQ * 25; o += NT) {
    int r = o / 25, ch = o % 25;
    const short* sp = xs_p + r * APS + ch * 16;
    s16x8 hh = *(const s16x8*)sp;
    s16x8 ll = *(const s16x8*)(sp + 8);
    float4 o0, o1;
    o0.x = joinf(hh[0], ll[0]); o0.y = joinf(hh[1], ll[1]);
    o0.z = joinf(hh[2], ll[2]); o0.w = joinf(hh[3], ll[3]);
    o1.x = joinf(hh[4], ll[4]); o1.y = joinf(hh[5], ll[5]);
    o1.z = joinf(hh[6], ll[6]); o1.w = joinf(hh[7], ll[7]);
    float* op = out + ((size_t)b * LQ + r) * DD + ch * 8;
    *(float4*)op = o0;
    *(float4*)(op + 4) = o1;
  }
}

extern "C" void kernel_launch(void* const* d_in, const int* in_sizes, int n_in,
                              void* d_out, int out_size, void* d_ws, size_t ws_size,
                              hipStream_t stream) {
  const int*   tokens = (const int*)  d_in[0];
  const float* emb    = (const float*)d_in[1];
  const float* Wq     = (const float*)d_in[2];
  const float* bq     = (const float*)d_in[3];
  const float* Wk     = (const float*)d_in[4];
  const float* bk     = (const float*)d_in[5];
  const float* Wv     = (const float*)d_in[6];
  const float* bv     = (const float*)d_in[7];
  const float* W1     = (const float*)d_in[8];
  const float* b1     = (const float*)d_in[9];
  const float* W2     = (const float*)d_in[10];
  const float* b2     = (const float*)d_in[11];
  const float* lng    = (const float*)d_in[12];
  const float* lnb    = (const float*)d_in[13];
  float* out = (float*)d_out;
  unsigned short* wbuf = (unsigned short*)d_ws;

  hipLaunchKernelGGL(swizzle_w, dim3(15 * KT * NTL), dim3(64), 0, stream,
                     Wq, Wk, Wv, W1, W2, wbuf);

  const int B = in_sizes[0] / LQ;   // 4096
  hipLaunchKernelGGL(transformer_kernel, dim3(B), dim3(NT), 0, stream,
                     tokens, emb, wbuf, bq, bk, bv, b1, b2, lng, lnb, out);
}